// Round 13
// baseline (716.048 us; speedup 1.0000x reference)
//
#include <hip/hip_runtime.h>
#include <hip/hip_bf16.h>
#include <math.h>

// Problem constants
#define NTOK 16384   // B*N = 4*4096
#define DM   1024
#define NQKV 3072
#define DFF  4096

typedef __bf16 bf16;
typedef __bf16 bf16x8 __attribute__((ext_vector_type(8)));
typedef float  f32x4  __attribute__((ext_vector_type(4)));

__device__ __forceinline__ void gload_lds16(const bf16* g, bf16* l) {
  __builtin_amdgcn_global_load_lds((const __attribute__((address_space(1))) void*)g,
                                   (__attribute__((address_space(3))) void*)l,
                                   16, 0, 0);
}

#define BAR()    asm volatile("s_barrier" ::: "memory")
#define SB0()    __builtin_amdgcn_sched_barrier(0)
#define LGKM0()  asm volatile("s_waitcnt lgkmcnt(0)" ::: "memory")
#define VMW(N)   asm volatile("s_waitcnt vmcnt(" #N ")" ::: "memory")

// ---------------- weight transpose + bf16 convert: src[K][N] fp32 -> dst[N][K] bf16 ----
__global__ __launch_bounds__(256)
void transpose_cvt(const float* __restrict__ src, bf16* __restrict__ dst, int K, int N)
{
  __shared__ float t[32][33];
  const int tx = threadIdx.x & 31, ty = threadIdx.x >> 5;
  const int n0 = blockIdx.x * 32, k0 = blockIdx.y * 32;
#pragma unroll
  for (int i = 0; i < 4; ++i)
    t[ty + 8*i][tx] = src[(size_t)(k0 + ty + 8*i) * N + n0 + tx];
  __syncthreads();
#pragma unroll
  for (int i = 0; i < 4; ++i)
    dst[(size_t)(n0 + ty + 8*i) * K + k0 + tx] = (bf16)t[tx][ty + 8*i];
}

__global__ void concat_bias(const float* __restrict__ bq, const float* __restrict__ bk,
                            const float* __restrict__ bv, float* __restrict__ o)
{
  int i = blockIdx.x * 256 + threadIdx.x;
  o[i] = (i < 1024) ? bq[i] : (i < 2048 ? bk[i - 1024] : bv[i - 2048]);
}

// ---------------- LayerNorm 1: x fp32 -> h bf16 --------------------------------------
__global__ __launch_bounds__(256)
void ln1_kernel(const float* __restrict__ x, const float* __restrict__ gamma,
                bf16* __restrict__ out)
{
  __shared__ float2 red[4];
  const int row = blockIdx.x, tid = threadIdx.x;
  const float4 v = ((const float4*)(x + (size_t)row * DM))[tid];
  float s  = v.x + v.y + v.z + v.w;
  float s2 = v.x*v.x + v.y*v.y + v.z*v.z + v.w*v.w;
#pragma unroll
  for (int m = 32; m >= 1; m >>= 1) { s += __shfl_xor(s, m); s2 += __shfl_xor(s2, m); }
  if ((tid & 63) == 0) red[tid >> 6] = make_float2(s, s2);
  __syncthreads();
  float S  = red[0].x + red[1].x + red[2].x + red[3].x;
  float S2 = red[0].y + red[1].y + red[2].y + red[3].y;
  const float mean = S * (1.0f / DM);
  const float var  = S2 * (1.0f / DM) - mean * mean;
  const float rs   = rsqrtf(var + 1e-5f);
  const float4 g = ((const float4*)gamma)[tid];
  union { bf16 b[4]; uint2 u; } o;
  o.b[0] = (bf16)((v.x - mean) * rs * g.x);
  o.b[1] = (bf16)((v.y - mean) * rs * g.y);
  o.b[2] = (bf16)((v.z - mean) * rs * g.z);
  o.b[3] = (bf16)((v.w - mean) * rs * g.w);
  *(uint2*)(out + (size_t)row * DM + tid * 4) = o.u;
}

// ---------------- LayerNorm 2 (double LN): xnew fp32 -> h2 bf16 ----------------------
__global__ __launch_bounds__(256)
void ln2_kernel(const float* __restrict__ x, const float* __restrict__ gamma,
                const float* __restrict__ ffg, const float* __restrict__ ffb,
                bf16* __restrict__ out)
{
  __shared__ float2 red[4];
  const int row = blockIdx.x, tid = threadIdx.x;
  const float4 v = ((const float4*)(x + (size_t)row * DM))[tid];
  float s  = v.x + v.y + v.z + v.w;
  float s2 = v.x*v.x + v.y*v.y + v.z*v.z + v.w*v.w;
#pragma unroll
  for (int m = 32; m >= 1; m >>= 1) { s += __shfl_xor(s, m); s2 += __shfl_xor(s2, m); }
  if ((tid & 63) == 0) red[tid >> 6] = make_float2(s, s2);
  __syncthreads();
  float S  = red[0].x + red[1].x + red[2].x + red[3].x;
  float S2 = red[0].y + red[1].y + red[2].y + red[3].y;
  float mean = S * (1.0f / DM);
  float var  = S2 * (1.0f / DM) - mean * mean;
  float rs   = rsqrtf(var + 1e-5f);
  const float4 g = ((const float4*)ffg)[tid];
  const float4 gg = ((const float4*)gamma)[tid];
  float y0 = (v.x - mean) * rs * gg.x;
  float y1 = (v.y - mean) * rs * gg.y;
  float y2 = (v.z - mean) * rs * gg.z;
  float y3 = (v.w - mean) * rs * gg.w;
  __syncthreads();  // red[] reuse
  s  = y0 + y1 + y2 + y3;
  s2 = y0*y0 + y1*y1 + y2*y2 + y3*y3;
#pragma unroll
  for (int m = 32; m >= 1; m >>= 1) { s += __shfl_xor(s, m); s2 += __shfl_xor(s2, m); }
  if ((tid & 63) == 0) red[tid >> 6] = make_float2(s, s2);
  __syncthreads();
  S  = red[0].x + red[1].x + red[2].x + red[3].x;
  S2 = red[0].y + red[1].y + red[2].y + red[3].y;
  mean = S * (1.0f / DM);
  var  = S2 * (1.0f / DM) - mean * mean;
  rs   = rsqrtf(var + 1e-5f);
  const float4 bb = ((const float4*)ffb)[tid];
  union { bf16 b[4]; uint2 u; } o;
  o.b[0] = (bf16)((y0 - mean) * rs * g.x + bb.x);
  o.b[1] = (bf16)((y1 - mean) * rs * g.y + bb.y);
  o.b[2] = (bf16)((y2 - mean) * rs * g.z + bb.z);
  o.b[3] = (bf16)((y3 - mean) * rs * g.w + bb.w);
  *(uint2*)(out + (size_t)row * DM + tid * 4) = o.u;
}

// ================ 128x128 GEMM — BK=32 double-buffer, counted vmcnt, 4 blocks/CU ======
// C[M x N] = A[M x K](bf16,lda) @ Bt[N x K]^T + bias ; EPI 0 bf16, 1 fp32+res, 2 gelu bf16
// 4 waves (2M x 2N), BK=32, LDS 32KB = 2 x {A[128][32] | B[128][32]} (16 KB buffers).
// Counted vmcnt: stage tile t+2 into the just-read buffer, VMW(4) retires only t+1.
// LDS swizzle (FIXED r13): slot s of row r holds global granule s ^ (r&3) ^ ((r>>2)&3).
// Bank audit: bank-start = 16*(r&1) + 4*s; per 16-lane read group the (parity,slot)
// pair = (c&1, lg^c^q), c=l16&3, q=l16>>2 -> each of 8 bank-quads gets exactly 2 lanes
// = free (m136). r12's s = lg^(r&3) was a function of l16&3 only -> 4-way conflict.

template<int EPI>
__global__ __launch_bounds__(256, 4)
void gemm128(const bf16* __restrict__ A, int lda,
             const bf16* __restrict__ Bt,
             const float* __restrict__ bias,
             const float* res, int ldres,
             void* Cout, int ldc, int K, int nblk)
{
  __shared__ __align__(16) bf16 lds[16384];   // 32 KB: two 16KB tile buffers
  const int tid = threadIdx.x, lane = tid & 63, wave = tid >> 6;
  const int wm = wave >> 1, wn = wave & 1;
  const int l16 = lane & 15, lg = lane >> 4;

  // XCD-aware swizzle (nblk % 8 == 0); M = 16384 -> 128 row blocks
  int id = blockIdx.x;
  id = (id & 7) * (nblk >> 3) + (id >> 3);
  const int row0 = (id & 127) << 7;
  const int col0 = (id >> 7) << 7;
  const int NT = K >> 5;   // 32 or 128 — always even, >= 4

  // ---- staging byte offsets (2 A + 2 B granule-loads per thread; += 64 B per tile) --
  const char* Ab = (const char*)A;
  const char* Bb = (const char*)Bt;
  unsigned oA[2], oB[2];
  {
    const int lc = tid & 3;           // granule slot within 32-elem row
#pragma unroll
    for (int it = 0; it < 2; ++it) {
      const int r = it * 64 + (tid >> 2);     // tile row 0..127
      const int gc = ((lc ^ (r & 3) ^ ((r >> 2) & 3)) << 3);  // pre-swizzled src granule
      oA[it] = (unsigned)(((row0 + r) * lda + gc) * 2);
      oB[it] = (unsigned)(((col0 + r) * K   + gc) * 2);
    }
  }

  // buffer layout (elements): A at BASE, B at BASE+4096; BASE in {0, 8192}
#define STAGE(BASE) do { \
    gload_lds16((const bf16*)(Ab + oA[0]), lds + (BASE)        + tid * 8); \
    gload_lds16((const bf16*)(Ab + oA[1]), lds + (BASE) + 2048 + tid * 8); \
    gload_lds16((const bf16*)(Bb + oB[0]), lds + (BASE) + 4096 + tid * 8); \
    gload_lds16((const bf16*)(Bb + oB[1]), lds + (BASE) + 6144 + tid * 8); \
    oA[0] += 64; oA[1] += 64; oB[0] += 64; oB[1] += 64; } while (0)

  // ---- frag LDS element offsets (iteration-invariant, swizzle baked in) ------------
  int aoff[4], boff[4];
#pragma unroll
  for (int i = 0; i < 4; ++i) {
    const int ra = wm * 64 + i * 16 + l16;
    const int rb = wn * 64 + i * 16 + l16;
    aoff[i] = ra * 32 + ((lg ^ (ra & 3) ^ ((ra >> 2) & 3)) << 3);
    boff[i] = 4096 + rb * 32 + ((lg ^ (rb & 3) ^ ((rb >> 2) & 3)) << 3);
  }

  f32x4 acc[4][4] = {};

  // Invariant entering body for tile TI (buffer BASE): TI landed + published;
  // TI+1's 4 loads in flight into the other buffer.
#define TILEC(BASE, TI) do { \
    bf16x8 af[4], bfr[4]; \
    _Pragma("unroll") \
    for (int i = 0; i < 4; ++i) { \
      af[i]  = *(const bf16x8*)&lds[(BASE) + aoff[i]]; \
      bfr[i] = *(const bf16x8*)&lds[(BASE) + boff[i]]; \
    } \
    _Pragma("unroll") \
    for (int j = 0; j < 4; ++j) \
      _Pragma("unroll") \
      for (int i = 0; i < 4; ++i) \
        acc[i][j] = __builtin_amdgcn_mfma_f32_16x16x32_bf16(af[i], bfr[j], acc[i][j], 0, 0, 0); \
    LGKM0(); SB0(); \
    BAR(); \
    if ((TI) + 2 < NT) { STAGE(BASE); VMW(4); } \
    else { VMW(0); } \
    BAR(); } while (0)

  // ---- prologue: stage tiles 0 and 1; retire tile 0, keep tile 1's 4 in flight -----
  STAGE(0);
  STAGE(8192);
  VMW(4);
  BAR();

  for (int t = 0; t < NT; t += 2) {
    TILEC(0, t);
    TILEC(8192, t + 1);
  }

  // ---- epilogue: per wave 64x64 at (row0+wm*64, col0+wn*64) ------------------------
#pragma unroll
  for (int i = 0; i < 4; ++i) {
    const int m0 = row0 + wm * 64 + i * 16 + lg * 4;
#pragma unroll
    for (int j = 0; j < 4; ++j) {
      const int n = col0 + wn * 64 + j * 16 + l16;
      const float bv = bias[n];
#pragma unroll
      for (int r = 0; r < 4; ++r) {
        const long m = m0 + r;
        float v = acc[i][j][r] + bv;
        if constexpr (EPI == 0) {
          ((bf16*)Cout)[m * ldc + n] = (bf16)v;
        } else if constexpr (EPI == 1) {
          ((float*)Cout)[m * ldc + n] = v + res[m * ldres + n];
        } else {
          // tanh-form GELU (max |diff| vs exact-erf GELU ~3e-3, NaN-safe at +-inf)
          const float u  = 0.79788456080286536f * (v + 0.044715f * v * v * v);
          const float e  = __expf(2.0f * u);
          const float th = 1.0f - 2.0f / (e + 1.0f);
          ((bf16*)Cout)[m * ldc + n] = (bf16)(0.5f * v * (1.0f + th));
        }
      }
    }
  }
}

// ---------------- dilated attention: one wave per (b, g, h) --------------------------
__global__ __launch_bounds__(64)
void attn_kernel(bf16* qkv)
{
  __shared__ bf16 Plds[32 * 32];
  __shared__ bf16 vT[64 * 32];
  const int blk = blockIdx.x;
  const int h = blk & 15;
  const int g = (blk >> 4) & 63;
  const int b = blk >> 10;
  const int par = h & 1;
  const int lane = threadIdx.x;
  const int l16 = lane & 15, lg = lane >> 4;
  const long base = ((long)b * 4096 + g * 64) * NQKV;

  bf16x8 qf[2][2], kf[2][2];
#pragma unroll
  for (int mb = 0; mb < 2; ++mb) {
    const int s = par + 2 * (mb * 16 + l16);
    const bf16* qrow = qkv + base + (long)s * NQKV + h * 64;
#pragma unroll
    for (int kk = 0; kk < 2; ++kk) {
      qf[mb][kk] = *(const bf16x8*)(qrow + kk * 32 + lg * 8);
      kf[mb][kk] = *(const bf16x8*)(qrow + 1024 + kk * 32 + lg * 8);
    }
  }

#pragma unroll
  for (int it = 0; it < 4; ++it) {
    const int kr  = it * 8 + (lane >> 3);
    const int dh0 = (lane & 7) * 8;
    const int s = par + 2 * kr;
    union { uint4 u; bf16 e[8]; } vv;
    vv.u = *(const uint4*)(qkv + base + (long)s * NQKV + 2048 + h * 64 + dh0);
#pragma unroll
    for (int j = 0; j < 8; ++j)
      vT[(dh0 + j) * 32 + kr] = vv.e[j];
  }

  f32x4 sc[2][2] = {};
#pragma unroll
  for (int mb = 0; mb < 2; ++mb)
#pragma unroll
    for (int nb = 0; nb < 2; ++nb)
#pragma unroll
      for (int kk = 0; kk < 2; ++kk)
        sc[mb][nb] = __builtin_amdgcn_mfma_f32_16x16x32_bf16(qf[mb][kk], kf[nb][kk], sc[mb][nb], 0, 0, 0);

  float pr[2][2][4];
#pragma unroll
  for (int mb = 0; mb < 2; ++mb)
#pragma unroll
    for (int r = 0; r < 4; ++r) {
      float a0 = sc[mb][0][r] * 0.125f, a1 = sc[mb][1][r] * 0.125f;
      float mx = fmaxf(a0, a1);
#pragma unroll
      for (int msk = 8; msk >= 1; msk >>= 1) mx = fmaxf(mx, __shfl_xor(mx, msk));
      float e0 = expf(a0 - mx), e1 = expf(a1 - mx);
      float sm = e0 + e1;
#pragma unroll
      for (int msk = 8; msk >= 1; msk >>= 1) sm += __shfl_xor(sm, msk);
      float inv = 1.0f / sm;
      pr[mb][0][r] = e0 * inv;
      pr[mb][1][r] = e1 * inv;
    }

  __syncthreads();
#pragma unroll
  for (int mb = 0; mb < 2; ++mb)
#pragma unroll
    for (int nb = 0; nb < 2; ++nb)
#pragma unroll
      for (int r = 0; r < 4; ++r)
        Plds[(mb * 16 + lg * 4 + r) * 32 + nb * 16 + l16] = (bf16)pr[mb][nb][r];
  __syncthreads();

  bf16x8 pa[2], vb[4];
#pragma unroll
  for (int mb = 0; mb < 2; ++mb)
    pa[mb] = *(const bf16x8*)&Plds[(mb * 16 + l16) * 32 + lg * 8];
#pragma unroll
  for (int nb = 0; nb < 4; ++nb)
    vb[nb] = *(const bf16x8*)&vT[(nb * 16 + l16) * 32 + lg * 8];
  f32x4 oc[2][4] = {};
#pragma unroll
  for (int mb = 0; mb < 2; ++mb)
#pragma unroll
    for (int nb = 0; nb < 4; ++nb)
      oc[mb][nb] = __builtin_amdgcn_mfma_f32_16x16x32_bf16(pa[mb], vb[nb], oc[mb][nb], 0, 0, 0);

#pragma unroll
  for (int mb = 0; mb < 2; ++mb)
#pragma unroll
    for (int nb = 0; nb < 4; ++nb)
#pragma unroll
      for (int r = 0; r < 4; ++r) {
        const int m = mb * 16 + lg * 4 + r;
        const int s = par + 2 * m;
        qkv[base + (long)s * NQKV + h * 64 + nb * 16 + l16] = (bf16)oc[mb][nb][r];
      }
  const uint4 z = make_uint4(0, 0, 0, 0);
#pragma unroll
  for (int it = 0; it < 4; ++it) {
    const int r2 = it * 8 + (lane >> 3);
    const int s = (1 - par) + 2 * r2;
    *(uint4*)(qkv + base + (long)s * NQKV + h * 64 + (lane & 7) * 8) = z;
  }
}

// ---------------- host-side orchestration --------------------------------------------
extern "C" void kernel_launch(void* const* d_in, const int* in_sizes, int n_in,
                              void* d_out, int out_size, void* d_ws, size_t ws_size,
                              hipStream_t stream)
{
  const float* x     = (const float*)d_in[0];
  const float* gamma = (const float*)d_in[1];
  const float* wq = (const float*)d_in[2];  const float* bq = (const float*)d_in[3];
  const float* wk = (const float*)d_in[4];  const float* bk = (const float*)d_in[5];
  const float* wv = (const float*)d_in[6];  const float* bv = (const float*)d_in[7];
  const float* wo = (const float*)d_in[8];  const float* bo = (const float*)d_in[9];
  const float* ffg = (const float*)d_in[10]; const float* ffb = (const float*)d_in[11];
  const float* w1 = (const float*)d_in[12]; const float* b1 = (const float*)d_in[13];
  const float* w2 = (const float*)d_in[14]; const float* b2 = (const float*)d_in[15];

  char* p = (char*)d_ws;
  bf16* Wqkv_t = (bf16*)p; p += (size_t)NQKV * DM * 2;
  bf16* Wo_t   = (bf16*)p; p += (size_t)DM * DM * 2;
  bf16* W1_t   = (bf16*)p; p += (size_t)DFF * DM * 2;
  bf16* W2_t   = (bf16*)p; p += (size_t)DM * DFF * 2;
  float* bqkv  = (float*)p; p += (size_t)NQKV * 4;
  bf16* hbuf   = (bf16*)p; p += (size_t)NTOK * DM * 2;
  bf16* qkv    = (bf16*)p; p += (size_t)NTOK * DFF * 2;
  float* xnew  = (float*)d_out;

  dim3 b256(256);
  transpose_cvt<<<dim3(32, 32),  b256, 0, stream>>>(wq, Wqkv_t,               DM, DM);
  transpose_cvt<<<dim3(32, 32),  b256, 0, stream>>>(wk, Wqkv_t + 1024 * 1024, DM, DM);
  transpose_cvt<<<dim3(32, 32),  b256, 0, stream>>>(wv, Wqkv_t + 2048 * 1024, DM, DM);
  transpose_cvt<<<dim3(32, 32),  b256, 0, stream>>>(wo, Wo_t, DM, DM);
  transpose_cvt<<<dim3(128, 32), b256, 0, stream>>>(w1, W1_t, DM, DFF);
  transpose_cvt<<<dim3(32, 128), b256, 0, stream>>>(w2, W2_t, DFF, DM);
  concat_bias<<<12, b256, 0, stream>>>(bq, bk, bv, bqkv);

  ln1_kernel<<<NTOK, b256, 0, stream>>>(x, gamma, hbuf);

  // QKV GEMM: h @ [wq|wk|wv] -> qkv bf16 [16384][3072]
  gemm128<0><<<dim3(128 * 24), b256, 0, stream>>>(
      hbuf, DM, Wqkv_t, bqkv, nullptr, 0, qkv, NQKV, DM, 128 * 24);

  attn_kernel<<<4096, dim3(64), 0, stream>>>(qkv);

  // WO GEMM + residual -> xnew fp32 (d_out)
  gemm128<1><<<dim3(128 * 8), b256, 0, stream>>>(
      qkv, NQKV, Wo_t, bo, x, DM, xnew, DM, DM, 128 * 8);

  ln2_kernel<<<NTOK, b256, 0, stream>>>(xnew, gamma, ffg, ffb, hbuf);

  // FFN1 + GELU -> g1 bf16 [16384][4096]
  gemm128<2><<<dim3(128 * 32), b256, 0, stream>>>(
      hbuf, DM, W1_t, b1, nullptr, 0, qkv, DFF, DM, 128 * 32);

  // FFN2 + residual -> d_out fp32
  gemm128<1><<<dim3(128 * 8), b256, 0, stream>>>(
      qkv, DFF, W2_t, b2, xnew, DM, (float*)d_out, DM, DFF, 128 * 8);
}

// Round 14
// 697.641 us; speedup vs baseline: 1.0264x; 1.0264x over previous
//
#include <hip/hip_runtime.h>
#include <hip/hip_bf16.h>
#include <math.h>

// Problem constants
#define NTOK 16384   // B*N = 4*4096
#define DM   1024
#define NQKV 3072
#define DFF  4096

typedef __bf16 bf16;
typedef __bf16 bf16x8 __attribute__((ext_vector_type(8)));
typedef float  f32x4  __attribute__((ext_vector_type(4)));

__device__ __forceinline__ void gload_lds16(const bf16* g, bf16* l) {
  __builtin_amdgcn_global_load_lds((const __attribute__((address_space(1))) void*)g,
                                   (__attribute__((address_space(3))) void*)l,
                                   16, 0, 0);
}

#define BAR()    asm volatile("s_barrier" ::: "memory")
#define SB0()    __builtin_amdgcn_sched_barrier(0)
#define LGKM0()  asm volatile("s_waitcnt lgkmcnt(0)" ::: "memory")
#define VMW(N)   asm volatile("s_waitcnt vmcnt(" #N ")" ::: "memory")

__device__ __forceinline__ float fast_gelu(float v) {
  // tanh-form GELU (max |diff| vs exact-erf GELU ~3e-3, NaN-safe at +-inf)
  const float u  = 0.79788456080286536f * (v + 0.044715f * v * v * v);
  const float e  = __expf(2.0f * u);
  const float th = 1.0f - 2.0f / (e + 1.0f);
  return 0.5f * v * (1.0f + th);
}

// ---------------- weight transpose + bf16 convert: src[K][N] fp32 -> dst[N][K] bf16 ----
__global__ __launch_bounds__(256)
void transpose_cvt(const float* __restrict__ src, bf16* __restrict__ dst, int K, int N)
{
  __shared__ float t[32][33];
  const int tx = threadIdx.x & 31, ty = threadIdx.x >> 5;
  const int n0 = blockIdx.x * 32, k0 = blockIdx.y * 32;
#pragma unroll
  for (int i = 0; i < 4; ++i)
    t[ty + 8*i][tx] = src[(size_t)(k0 + ty + 8*i) * N + n0 + tx];
  __syncthreads();
#pragma unroll
  for (int i = 0; i < 4; ++i)
    dst[(size_t)(n0 + ty + 8*i) * K + k0 + tx] = (bf16)t[tx][ty + 8*i];
}

__global__ void concat_bias(const float* __restrict__ bq, const float* __restrict__ bk,
                            const float* __restrict__ bv, float* __restrict__ o)
{
  int i = blockIdx.x * 256 + threadIdx.x;
  o[i] = (i < 1024) ? bq[i] : (i < 2048 ? bk[i - 1024] : bv[i - 2048]);
}

// ---------------- LayerNorm 1: x fp32 -> h bf16 --------------------------------------
__global__ __launch_bounds__(256)
void ln1_kernel(const float* __restrict__ x, const float* __restrict__ gamma,
                bf16* __restrict__ out)
{
  __shared__ float2 red[4];
  const int row = blockIdx.x, tid = threadIdx.x;
  const float4 v = ((const float4*)(x + (size_t)row * DM))[tid];
  float s  = v.x + v.y + v.z + v.w;
  float s2 = v.x*v.x + v.y*v.y + v.z*v.z + v.w*v.w;
#pragma unroll
  for (int m = 32; m >= 1; m >>= 1) { s += __shfl_xor(s, m); s2 += __shfl_xor(s2, m); }
  if ((tid & 63) == 0) red[tid >> 6] = make_float2(s, s2);
  __syncthreads();
  float S  = red[0].x + red[1].x + red[2].x + red[3].x;
  float S2 = red[0].y + red[1].y + red[2].y + red[3].y;
  const float mean = S * (1.0f / DM);
  const float var  = S2 * (1.0f / DM) - mean * mean;
  const float rs   = rsqrtf(var + 1e-5f);
  const float4 g = ((const float4*)gamma)[tid];
  union { bf16 b[4]; uint2 u; } o;
  o.b[0] = (bf16)((v.x - mean) * rs * g.x);
  o.b[1] = (bf16)((v.y - mean) * rs * g.y);
  o.b[2] = (bf16)((v.z - mean) * rs * g.z);
  o.b[3] = (bf16)((v.w - mean) * rs * g.w);
  *(uint2*)(out + (size_t)row * DM + tid * 4) = o.u;
}

// ---------------- LayerNorm 2 (double LN): xnew fp32 -> h2 bf16 ----------------------
__global__ __launch_bounds__(256)
void ln2_kernel(const float* __restrict__ x, const float* __restrict__ gamma,
                const float* __restrict__ ffg, const float* __restrict__ ffb,
                bf16* __restrict__ out)
{
  __shared__ float2 red[4];
  const int row = blockIdx.x, tid = threadIdx.x;
  const float4 v = ((const float4*)(x + (size_t)row * DM))[tid];
  float s  = v.x + v.y + v.z + v.w;
  float s2 = v.x*v.x + v.y*v.y + v.z*v.z + v.w*v.w;
#pragma unroll
  for (int m = 32; m >= 1; m >>= 1) { s += __shfl_xor(s, m); s2 += __shfl_xor(s2, m); }
  if ((tid & 63) == 0) red[tid >> 6] = make_float2(s, s2);
  __syncthreads();
  float S  = red[0].x + red[1].x + red[2].x + red[3].x;
  float S2 = red[0].y + red[1].y + red[2].y + red[3].y;
  float mean = S * (1.0f / DM);
  float var  = S2 * (1.0f / DM) - mean * mean;
  float rs   = rsqrtf(var + 1e-5f);
  const float4 g = ((const float4*)ffg)[tid];
  const float4 gg = ((const float4*)gamma)[tid];
  float y0 = (v.x - mean) * rs * gg.x;
  float y1 = (v.y - mean) * rs * gg.y;
  float y2 = (v.z - mean) * rs * gg.z;
  float y3 = (v.w - mean) * rs * gg.w;
  __syncthreads();  // red[] reuse
  s  = y0 + y1 + y2 + y3;
  s2 = y0*y0 + y1*y1 + y2*y2 + y3*y3;
#pragma unroll
  for (int m = 32; m >= 1; m >>= 1) { s += __shfl_xor(s, m); s2 += __shfl_xor(s2, m); }
  if ((tid & 63) == 0) red[tid >> 6] = make_float2(s, s2);
  __syncthreads();
  S  = red[0].x + red[1].x + red[2].x + red[3].x;
  S2 = red[0].y + red[1].y + red[2].y + red[3].y;
  mean = S * (1.0f / DM);
  var  = S2 * (1.0f / DM) - mean * mean;
  rs   = rsqrtf(var + 1e-5f);
  const float4 bb = ((const float4*)ffb)[tid];
  union { bf16 b[4]; uint2 u; } o;
  o.b[0] = (bf16)((y0 - mean) * rs * g.x + bb.x);
  o.b[1] = (bf16)((y1 - mean) * rs * g.y + bb.y);
  o.b[2] = (bf16)((y2 - mean) * rs * g.z + bb.z);
  o.b[3] = (bf16)((y3 - mean) * rs * g.w + bb.w);
  *(uint2*)(out + (size_t)row * DM + tid * 4) = o.u;
}

// ============ kernel A: 128x128, BK=64, single 32KB buffer, drain (r8; K-deep) ========
// Best measured for K in {3072, 4096}: 0 bank conflicts, 4 blocks/CU TLP.
template<int EPI>
__global__ __launch_bounds__(256, 4)
void gemm64d(const bf16* __restrict__ A, int lda,
             const bf16* __restrict__ Bt,
             const float* __restrict__ bias,
             const float* res, int ldres,
             void* Cout, int ldc, int K, int nblk)
{
  __shared__ __align__(16) bf16 lds[16384];   // 32 KB: A[128][64] | B[128][64]
  const int tid = threadIdx.x, lane = tid & 63, wave = tid >> 6;
  const int wm = wave >> 1, wn = wave & 1;
  const int l16 = lane & 15, lg = lane >> 4;

  int id = blockIdx.x;
  id = (id & 7) * (nblk >> 3) + (id >> 3);
  const int row0 = (id & 127) << 7;
  const int col0 = (id >> 7) << 7;
  const int NT = K >> 6;

  const char* Ab = (const char*)A;
  const char* Bb = (const char*)Bt;
  unsigned oA[4], oB[4];
  {
    const int lr = tid >> 3;
    const int lc = tid & 7;
#pragma unroll
    for (int it = 0; it < 4; ++it) {
      const int r = it * 32 + lr;
      const int gc = ((lc ^ (r & 7)) << 3);
      oA[it] = (unsigned)(((row0 + r) * lda + gc) * 2);
      oB[it] = (unsigned)(((col0 + r) * K   + gc) * 2);
    }
  }

#define STAGE64() do { \
    gload_lds16((const bf16*)(Ab + oA[0]), lds         + tid * 8); \
    gload_lds16((const bf16*)(Ab + oA[1]), lds + 2048  + tid * 8); \
    gload_lds16((const bf16*)(Ab + oA[2]), lds + 4096  + tid * 8); \
    gload_lds16((const bf16*)(Ab + oA[3]), lds + 6144  + tid * 8); \
    gload_lds16((const bf16*)(Bb + oB[0]), lds + 8192  + tid * 8); \
    gload_lds16((const bf16*)(Bb + oB[1]), lds + 10240 + tid * 8); \
    gload_lds16((const bf16*)(Bb + oB[2]), lds + 12288 + tid * 8); \
    gload_lds16((const bf16*)(Bb + oB[3]), lds + 14336 + tid * 8); \
    oA[0] += 128; oA[1] += 128; oA[2] += 128; oA[3] += 128; \
    oB[0] += 128; oB[1] += 128; oB[2] += 128; oB[3] += 128; } while (0)

  int aoff[4][2], boff[4][2];
#pragma unroll
  for (int i = 0; i < 4; ++i) {
    const int ra = wm * 64 + i * 16 + l16;
    const int rb = wn * 64 + i * 16 + l16;
#pragma unroll
    for (int kk = 0; kk < 2; ++kk) {
      aoff[i][kk] = ra * 64 + (((kk * 4 + lg) ^ (ra & 7)) << 3);
      boff[i][kk] = 8192 + rb * 64 + (((kk * 4 + lg) ^ (rb & 7)) << 3);
    }
  }

  f32x4 acc[4][4] = {};

  STAGE64();                    // tile 0
  for (int t = 0; t < NT; ++t) {
    __syncthreads();            // drains vmcnt(0): tile t landed in LDS
    bf16x8 af[4][2];
#pragma unroll
    for (int i = 0; i < 4; ++i) {
      af[i][0] = *(const bf16x8*)&lds[aoff[i][0]];
      af[i][1] = *(const bf16x8*)&lds[aoff[i][1]];
    }
#pragma unroll
    for (int j = 0; j < 4; ++j) {
      bf16x8 b0 = *(const bf16x8*)&lds[boff[j][0]];
      bf16x8 b1 = *(const bf16x8*)&lds[boff[j][1]];
#pragma unroll
      for (int i = 0; i < 4; ++i) {
        acc[i][j] = __builtin_amdgcn_mfma_f32_16x16x32_bf16(af[i][0], b0, acc[i][j], 0, 0, 0);
        acc[i][j] = __builtin_amdgcn_mfma_f32_16x16x32_bf16(af[i][1], b1, acc[i][j], 0, 0, 0);
      }
    }
    __syncthreads();            // all waves done reading tile t
    if (t + 1 < NT) STAGE64();
  }

#pragma unroll
  for (int i = 0; i < 4; ++i) {
    const int m0 = row0 + wm * 64 + i * 16 + lg * 4;
#pragma unroll
    for (int j = 0; j < 4; ++j) {
      const int n = col0 + wn * 64 + j * 16 + l16;
      const float bv = bias[n];
#pragma unroll
      for (int r = 0; r < 4; ++r) {
        const long m = m0 + r;
        float v = acc[i][j][r] + bv;
        if constexpr (EPI == 0) {
          ((bf16*)Cout)[m * ldc + n] = (bf16)v;
        } else if constexpr (EPI == 1) {
          ((float*)Cout)[m * ldc + n] = v + res[m * ldres + n];
        } else {
          ((bf16*)Cout)[m * ldc + n] = (bf16)fast_gelu(v);
        }
      }
    }
  }
}

// ============ kernel B: 128x128, BK=32 double-buffer, counted vmcnt (r13; K=1024) =====
// Best measured for K=1024 (FFN1 239->222 vs kernel A). Carries a structural
// 1-conflict-per-DMA-beat cost (~12%) that is swizzle-invariant (r12 vs r13 A/B).
template<int EPI>
__global__ __launch_bounds__(256, 4)
void gemm32c(const bf16* __restrict__ A, int lda,
             const bf16* __restrict__ Bt,
             const float* __restrict__ bias,
             const float* res, int ldres,
             void* Cout, int ldc, int K, int nblk)
{
  __shared__ __align__(16) bf16 lds[16384];   // 32 KB: two 16KB tile buffers
  const int tid = threadIdx.x, lane = tid & 63, wave = tid >> 6;
  const int wm = wave >> 1, wn = wave & 1;
  const int l16 = lane & 15, lg = lane >> 4;

  int id = blockIdx.x;
  id = (id & 7) * (nblk >> 3) + (id >> 3);
  const int row0 = (id & 127) << 7;
  const int col0 = (id >> 7) << 7;
  const int NT = K >> 5;

  const char* Ab = (const char*)A;
  const char* Bb = (const char*)Bt;
  unsigned oA[2], oB[2];
  {
    const int lc = tid & 3;
#pragma unroll
    for (int it = 0; it < 2; ++it) {
      const int r = it * 64 + (tid >> 2);
      const int gc = ((lc ^ (r & 3) ^ ((r >> 2) & 3)) << 3);
      oA[it] = (unsigned)(((row0 + r) * lda + gc) * 2);
      oB[it] = (unsigned)(((col0 + r) * K   + gc) * 2);
    }
  }

#define STAGE32(BASE) do { \
    gload_lds16((const bf16*)(Ab + oA[0]), lds + (BASE)        + tid * 8); \
    gload_lds16((const bf16*)(Ab + oA[1]), lds + (BASE) + 2048 + tid * 8); \
    gload_lds16((const bf16*)(Bb + oB[0]), lds + (BASE) + 4096 + tid * 8); \
    gload_lds16((const bf16*)(Bb + oB[1]), lds + (BASE) + 6144 + tid * 8); \
    oA[0] += 64; oA[1] += 64; oB[0] += 64; oB[1] += 64; } while (0)

  int aoff[4], boff[4];
#pragma unroll
  for (int i = 0; i < 4; ++i) {
    const int ra = wm * 64 + i * 16 + l16;
    const int rb = wn * 64 + i * 16 + l16;
    aoff[i] = ra * 32 + ((lg ^ (ra & 3) ^ ((ra >> 2) & 3)) << 3);
    boff[i] = 4096 + rb * 32 + ((lg ^ (rb & 3) ^ ((rb >> 2) & 3)) << 3);
  }

  f32x4 acc[4][4] = {};

#define TILE32(BASE, TI) do { \
    bf16x8 af[4], bfr[4]; \
    _Pragma("unroll") \
    for (int i = 0; i < 4; ++i) { \
      af[i]  = *(const bf16x8*)&lds[(BASE) + aoff[i]]; \
      bfr[i] = *(const bf16x8*)&lds[(BASE) + boff[i]]; \
    } \
    _Pragma("unroll") \
    for (int j = 0; j < 4; ++j) \
      _Pragma("unroll") \
      for (int i = 0; i < 4; ++i) \
        acc[i][j] = __builtin_amdgcn_mfma_f32_16x16x32_bf16(af[i], bfr[j], acc[i][j], 0, 0, 0); \
    LGKM0(); SB0(); \
    BAR(); \
    if ((TI) + 2 < NT) { STAGE32(BASE); VMW(4); } \
    else { VMW(0); } \
    BAR(); } while (0)

  STAGE32(0);
  STAGE32(8192);
  VMW(4);
  BAR();

  for (int t = 0; t < NT; t += 2) {
    TILE32(0, t);
    TILE32(8192, t + 1);
  }

#pragma unroll
  for (int i = 0; i < 4; ++i) {
    const int m0 = row0 + wm * 64 + i * 16 + lg * 4;
#pragma unroll
    for (int j = 0; j < 4; ++j) {
      const int n = col0 + wn * 64 + j * 16 + l16;
      const float bv = bias[n];
#pragma unroll
      for (int r = 0; r < 4; ++r) {
        const long m = m0 + r;
        float v = acc[i][j][r] + bv;
        if constexpr (EPI == 0) {
          ((bf16*)Cout)[m * ldc + n] = (bf16)v;
        } else if constexpr (EPI == 1) {
          ((float*)Cout)[m * ldc + n] = v + res[m * ldres + n];
        } else {
          ((bf16*)Cout)[m * ldc + n] = (bf16)fast_gelu(v);
        }
      }
    }
  }
}

// ---------------- dilated attention: one wave per (b, g, h) --------------------------
__global__ __launch_bounds__(64)
void attn_kernel(bf16* qkv)
{
  __shared__ bf16 Plds[32 * 32];
  __shared__ bf16 vT[64 * 32];
  const int blk = blockIdx.x;
  const int h = blk & 15;
  const int g = (blk >> 4) & 63;
  const int b = blk >> 10;
  const int par = h & 1;
  const int lane = threadIdx.x;
  const int l16 = lane & 15, lg = lane >> 4;
  const long base = ((long)b * 4096 + g * 64) * NQKV;

  bf16x8 qf[2][2], kf[2][2];
#pragma unroll
  for (int mb = 0; mb < 2; ++mb) {
    const int s = par + 2 * (mb * 16 + l16);
    const bf16* qrow = qkv + base + (long)s * NQKV + h * 64;
#pragma unroll
    for (int kk = 0; kk < 2; ++kk) {
      qf[mb][kk] = *(const bf16x8*)(qrow + kk * 32 + lg * 8);
      kf[mb][kk] = *(const bf16x8*)(qrow + 1024 + kk * 32 + lg * 8);
    }
  }

#pragma unroll
  for (int it = 0; it < 4; ++it) {
    const int kr  = it * 8 + (lane >> 3);
    const int dh0 = (lane & 7) * 8;
    const int s = par + 2 * kr;
    union { uint4 u; bf16 e[8]; } vv;
    vv.u = *(const uint4*)(qkv + base + (long)s * NQKV + 2048 + h * 64 + dh0);
#pragma unroll
    for (int j = 0; j < 8; ++j)
      vT[(dh0 + j) * 32 + kr] = vv.e[j];
  }

  f32x4 sc[2][2] = {};
#pragma unroll
  for (int mb = 0; mb < 2; ++mb)
#pragma unroll
    for (int nb = 0; nb < 2; ++nb)
#pragma unroll
      for (int kk = 0; kk < 2; ++kk)
        sc[mb][nb] = __builtin_amdgcn_mfma_f32_16x16x32_bf16(qf[mb][kk], kf[nb][kk], sc[mb][nb], 0, 0, 0);

  float pr[2][2][4];
#pragma unroll
  for (int mb = 0; mb < 2; ++mb)
#pragma unroll
    for (int r = 0; r < 4; ++r) {
      float a0 = sc[mb][0][r] * 0.125f, a1 = sc[mb][1][r] * 0.125f;
      float mx = fmaxf(a0, a1);
#pragma unroll
      for (int msk = 8; msk >= 1; msk >>= 1) mx = fmaxf(mx, __shfl_xor(mx, msk));
      float e0 = expf(a0 - mx), e1 = expf(a1 - mx);
      float sm = e0 + e1;
#pragma unroll
      for (int msk = 8; msk >= 1; msk >>= 1) sm += __shfl_xor(sm, msk);
      float inv = 1.0f / sm;
      pr[mb][0][r] = e0 * inv;
      pr[mb][1][r] = e1 * inv;
    }

  __syncthreads();
#pragma unroll
  for (int mb = 0; mb < 2; ++mb)
#pragma unroll
    for (int nb = 0; nb < 2; ++nb)
#pragma unroll
      for (int r = 0; r < 4; ++r)
        Plds[(mb * 16 + lg * 4 + r) * 32 + nb * 16 + l16] = (bf16)pr[mb][nb][r];
  __syncthreads();

  bf16x8 pa[2], vb[4];
#pragma unroll
  for (int mb = 0; mb < 2; ++mb)
    pa[mb] = *(const bf16x8*)&Plds[(mb * 16 + l16) * 32 + lg * 8];
#pragma unroll
  for (int nb = 0; nb < 4; ++nb)
    vb[nb] = *(const bf16x8*)&vT[(nb * 16 + l16) * 32 + lg * 8];
  f32x4 oc[2][4] = {};
#pragma unroll
  for (int mb = 0; mb < 2; ++mb)
#pragma unroll
    for (int nb = 0; nb < 4; ++nb)
      oc[mb][nb] = __builtin_amdgcn_mfma_f32_16x16x32_bf16(pa[mb], vb[nb], oc[mb][nb], 0, 0, 0);

#pragma unroll
  for (int mb = 0; mb < 2; ++mb)
#pragma unroll
    for (int nb = 0; nb < 4; ++nb)
#pragma unroll
      for (int r = 0; r < 4; ++r) {
        const int m = mb * 16 + lg * 4 + r;
        const int s = par + 2 * m;
        qkv[base + (long)s * NQKV + h * 64 + nb * 16 + l16] = (bf16)oc[mb][nb][r];
      }
  const uint4 z = make_uint4(0, 0, 0, 0);
#pragma unroll
  for (int it = 0; it < 4; ++it) {
    const int r2 = it * 8 + (lane >> 3);
    const int s = (1 - par) + 2 * r2;
    *(uint4*)(qkv + base + (long)s * NQKV + h * 64 + (lane & 7) * 8) = z;
  }
}

// ---------------- host-side orchestration --------------------------------------------
extern "C" void kernel_launch(void* const* d_in, const int* in_sizes, int n_in,
                              void* d_out, int out_size, void* d_ws, size_t ws_size,
                              hipStream_t stream)
{
  const float* x     = (const float*)d_in[0];
  const float* gamma = (const float*)d_in[1];
  const float* wq = (const float*)d_in[2];  const float* bq = (const float*)d_in[3];
  const float* wk = (const float*)d_in[4];  const float* bk = (const float*)d_in[5];
  const float* wv = (const float*)d_in[6];  const float* bv = (const float*)d_in[7];
  const float* wo = (const float*)d_in[8];  const float* bo = (const float*)d_in[9];
  const float* ffg = (const float*)d_in[10]; const float* ffb = (const float*)d_in[11];
  const float* w1 = (const float*)d_in[12]; const float* b1 = (const float*)d_in[13];
  const float* w2 = (const float*)d_in[14]; const float* b2 = (const float*)d_in[15];

  char* p = (char*)d_ws;
  bf16* Wqkv_t = (bf16*)p; p += (size_t)NQKV * DM * 2;
  bf16* Wo_t   = (bf16*)p; p += (size_t)DM * DM * 2;
  bf16* W1_t   = (bf16*)p; p += (size_t)DFF * DM * 2;
  bf16* W2_t   = (bf16*)p; p += (size_t)DM * DFF * 2;
  float* bqkv  = (float*)p; p += (size_t)NQKV * 4;
  bf16* hbuf   = (bf16*)p; p += (size_t)NTOK * DM * 2;
  bf16* qkv    = (bf16*)p; p += (size_t)NTOK * DFF * 2;
  float* xnew  = (float*)d_out;

  dim3 b256(256);
  transpose_cvt<<<dim3(32, 32),  b256, 0, stream>>>(wq, Wqkv_t,               DM, DM);
  transpose_cvt<<<dim3(32, 32),  b256, 0, stream>>>(wk, Wqkv_t + 1024 * 1024, DM, DM);
  transpose_cvt<<<dim3(32, 32),  b256, 0, stream>>>(wv, Wqkv_t + 2048 * 1024, DM, DM);
  transpose_cvt<<<dim3(32, 32),  b256, 0, stream>>>(wo, Wo_t, DM, DM);
  transpose_cvt<<<dim3(128, 32), b256, 0, stream>>>(w1, W1_t, DM, DFF);
  transpose_cvt<<<dim3(32, 128), b256, 0, stream>>>(w2, W2_t, DFF, DM);
  concat_bias<<<12, b256, 0, stream>>>(bq, bk, bv, bqkv);

  ln1_kernel<<<NTOK, b256, 0, stream>>>(x, gamma, hbuf);

  // QKV GEMM (K=1024 -> BK=32 counted): h @ [wq|wk|wv] -> qkv bf16 [16384][3072]
  gemm32c<0><<<dim3(128 * 24), b256, 0, stream>>>(
      hbuf, DM, Wqkv_t, bqkv, nullptr, 0, qkv, NQKV, DM, 128 * 24);

  attn_kernel<<<4096, dim3(64), 0, stream>>>(qkv);

  // WO GEMM (K=3072 -> BK=64 drain) + residual -> xnew fp32 (d_out)
  gemm64d<1><<<dim3(128 * 8), b256, 0, stream>>>(
      qkv, NQKV, Wo_t, bo, x, DM, xnew, DM, DM, 128 * 8);

  ln2_kernel<<<NTOK, b256, 0, stream>>>(xnew, gamma, ffg, ffb, hbuf);

  // FFN1 + GELU (K=1024 -> BK=32 counted) -> g1 bf16 [16384][4096]
  gemm32c<2><<<dim3(128 * 32), b256, 0, stream>>>(
      hbuf, DM, W1_t, b1, nullptr, 0, qkv, DFF, DM, 128 * 32);

  // FFN2 (K=4096 -> BK=64 drain) + residual -> d_out fp32
  gemm64d<1><<<dim3(128 * 8), b256, 0, stream>>>(
      qkv, DFF, W2_t, b2, xnew, DM, (float*)d_out, DM, DFF, 128 * 8);
}

// Round 15
// 653.884 us; speedup vs baseline: 1.0951x; 1.0669x over previous
//
#include <hip/hip_runtime.h>
#include <hip/hip_bf16.h>
#include <math.h>

// Problem constants
#define NTOK 16384   // B*N = 4*4096
#define DM   1024
#define NQKV 3072
#define DFF  4096

typedef __bf16 bf16;
typedef __bf16 bf16x8 __attribute__((ext_vector_type(8)));
typedef float  f32x4  __attribute__((ext_vector_type(4)));

__device__ __forceinline__ void gload_lds16(const bf16* g, bf16* l) {
  __builtin_amdgcn_global_load_lds((const __attribute__((address_space(1))) void*)g,
                                   (__attribute__((address_space(3))) void*)l,
                                   16, 0, 0);
}

#define BAR()    asm volatile("s_barrier" ::: "memory")
#define SB0()    __builtin_amdgcn_sched_barrier(0)
#define LGKM0()  asm volatile("s_waitcnt lgkmcnt(0)" ::: "memory")
#define VMW(N)   asm volatile("s_waitcnt vmcnt(" #N ")" ::: "memory")

__device__ __forceinline__ float fast_gelu(float v) {
  const float u  = 0.79788456080286536f * (v + 0.044715f * v * v * v);
  const float e  = __expf(2.0f * u);
  const float th = 1.0f - 2.0f / (e + 1.0f);
  return 0.5f * v * (1.0f + th);
}

// Tiled-swizzled layout for gemm32c operands: [blk128][kblk32][128][32] bf16, 8KB/tile;
// within a tile row r, granule slot s holds source granule s ^ (r&3) ^ ((r>>2)&3).
__device__ __forceinline__ size_t tile_off(int rowg, int k, int KB) {
  const int rr = rowg & 127;
  const int swz = (rr & 3) ^ ((rr >> 2) & 3);
  const int slot = ((k >> 3) & 3) ^ swz;
  return ((size_t)(rowg >> 7) * KB + (k >> 5)) * 4096 + rr * 32 + slot * 8 + (k & 7);
}

// ---------------- weight transpose (row-major out): src[K][N] fp32 -> dst[N][K] bf16 --
__global__ __launch_bounds__(256)
void transpose_cvt(const float* __restrict__ src, bf16* __restrict__ dst, int K, int N)
{
  __shared__ float t[32][33];
  const int tx = threadIdx.x & 31, ty = threadIdx.x >> 5;
  const int n0 = blockIdx.x * 32, k0 = blockIdx.y * 32;
#pragma unroll
  for (int i = 0; i < 4; ++i)
    t[ty + 8*i][tx] = src[(size_t)(k0 + ty + 8*i) * N + n0 + tx];
  __syncthreads();
#pragma unroll
  for (int i = 0; i < 4; ++i)
    dst[(size_t)(n0 + ty + 8*i) * K + k0 + tx] = (bf16)t[tx][ty + 8*i];
}

// ---------------- weight transpose (tiled-swizzled out) -------------------------------
// srcs z=0/1/2 each [K][Nper] fp32; dst rows z*Nper + n. KB = K/32.
__global__ __launch_bounds__(256)
void transpose_cvt_tiled(const float* __restrict__ s0, const float* __restrict__ s1,
                         const float* __restrict__ s2, bf16* __restrict__ dst,
                         int K, int Nper)
{
  __shared__ float t[32][33];
  const int tx = threadIdx.x & 31, ty = threadIdx.x >> 5;
  const int n0 = blockIdx.x * 32, k0 = blockIdx.y * 32;
  const int z = blockIdx.z;
  const float* src = (z == 0) ? s0 : (z == 1) ? s1 : s2;
  const int KB = K >> 5;
#pragma unroll
  for (int i = 0; i < 4; ++i)
    t[ty + 8*i][tx] = src[(size_t)(k0 + ty + 8*i) * Nper + n0 + tx];
  __syncthreads();
#pragma unroll
  for (int i = 0; i < 4; ++i) {
    const int ng = z * Nper + n0 + ty + 8*i;
    dst[tile_off(ng, k0 + tx, KB)] = (bf16)t[tx][ty + 8*i];
  }
}

__global__ void concat_bias(const float* __restrict__ bq, const float* __restrict__ bk,
                            const float* __restrict__ bv, float* __restrict__ o)
{
  int i = blockIdx.x * 256 + threadIdx.x;
  o[i] = (i < 1024) ? bq[i] : (i < 2048 ? bk[i - 1024] : bv[i - 2048]);
}

// ---------------- LayerNorm 1: x fp32 -> h bf16 (tiled-swizzled) ----------------------
__global__ __launch_bounds__(256)
void ln1_kernel(const float* __restrict__ x, const float* __restrict__ gamma,
                bf16* __restrict__ out)
{
  __shared__ float2 red[4];
  const int row = blockIdx.x, tid = threadIdx.x;
  const float4 v = ((const float4*)(x + (size_t)row * DM))[tid];
  float s  = v.x + v.y + v.z + v.w;
  float s2 = v.x*v.x + v.y*v.y + v.z*v.z + v.w*v.w;
#pragma unroll
  for (int m = 32; m >= 1; m >>= 1) { s += __shfl_xor(s, m); s2 += __shfl_xor(s2, m); }
  if ((tid & 63) == 0) red[tid >> 6] = make_float2(s, s2);
  __syncthreads();
  float S  = red[0].x + red[1].x + red[2].x + red[3].x;
  float S2 = red[0].y + red[1].y + red[2].y + red[3].y;
  const float mean = S * (1.0f / DM);
  const float var  = S2 * (1.0f / DM) - mean * mean;
  const float rs   = rsqrtf(var + 1e-5f);
  const float4 g = ((const float4*)gamma)[tid];
  union { bf16 b[4]; uint2 u; } o;
  o.b[0] = (bf16)((v.x - mean) * rs * g.x);
  o.b[1] = (bf16)((v.y - mean) * rs * g.y);
  o.b[2] = (bf16)((v.z - mean) * rs * g.z);
  o.b[3] = (bf16)((v.w - mean) * rs * g.w);
  *(uint2*)(out + tile_off(row, tid * 4, DM >> 5)) = o.u;
}

// ---------------- LayerNorm 2 (double LN): xnew fp32 -> h2 bf16 (tiled-swizzled) ------
__global__ __launch_bounds__(256)
void ln2_kernel(const float* __restrict__ x, const float* __restrict__ gamma,
                const float* __restrict__ ffg, const float* __restrict__ ffb,
                bf16* __restrict__ out)
{
  __shared__ float2 red[4];
  const int row = blockIdx.x, tid = threadIdx.x;
  const float4 v = ((const float4*)(x + (size_t)row * DM))[tid];
  float s  = v.x + v.y + v.z + v.w;
  float s2 = v.x*v.x + v.y*v.y + v.z*v.z + v.w*v.w;
#pragma unroll
  for (int m = 32; m >= 1; m >>= 1) { s += __shfl_xor(s, m); s2 += __shfl_xor(s2, m); }
  if ((tid & 63) == 0) red[tid >> 6] = make_float2(s, s2);
  __syncthreads();
  float S  = red[0].x + red[1].x + red[2].x + red[3].x;
  float S2 = red[0].y + red[1].y + red[2].y + red[3].y;
  float mean = S * (1.0f / DM);
  float var  = S2 * (1.0f / DM) - mean * mean;
  float rs   = rsqrtf(var + 1e-5f);
  const float4 g = ((const float4*)ffg)[tid];
  const float4 gg = ((const float4*)gamma)[tid];
  float y0 = (v.x - mean) * rs * gg.x;
  float y1 = (v.y - mean) * rs * gg.y;
  float y2 = (v.z - mean) * rs * gg.z;
  float y3 = (v.w - mean) * rs * gg.w;
  __syncthreads();  // red[] reuse
  s  = y0 + y1 + y2 + y3;
  s2 = y0*y0 + y1*y1 + y2*y2 + y3*y3;
#pragma unroll
  for (int m = 32; m >= 1; m >>= 1) { s += __shfl_xor(s, m); s2 += __shfl_xor(s2, m); }
  if ((tid & 63) == 0) red[tid >> 6] = make_float2(s, s2);
  __syncthreads();
  S  = red[0].x + red[1].x + red[2].x + red[3].x;
  S2 = red[0].y + red[1].y + red[2].y + red[3].y;
  mean = S * (1.0f / DM);
  var  = S2 * (1.0f / DM) - mean * mean;
  rs   = rsqrtf(var + 1e-5f);
  const float4 bb = ((const float4*)ffb)[tid];
  union { bf16 b[4]; uint2 u; } o;
  o.b[0] = (bf16)((y0 - mean) * rs * g.x + bb.x);
  o.b[1] = (bf16)((y1 - mean) * rs * g.y + bb.y);
  o.b[2] = (bf16)((y2 - mean) * rs * g.z + bb.z);
  o.b[3] = (bf16)((y3 - mean) * rs * g.w + bb.w);
  *(uint2*)(out + tile_off(row, tid * 4, DM >> 5)) = o.u;
}

// ============ kernel A: 128x128, BK=64, single 32KB buffer, drain (K-deep) ============
template<int EPI>
__global__ __launch_bounds__(256, 4)
void gemm64d(const bf16* __restrict__ A, int lda,
             const bf16* __restrict__ Bt,
             const float* __restrict__ bias,
             const float* res, int ldres,
             void* Cout, int ldc, int K, int nblk)
{
  __shared__ __align__(16) bf16 lds[16384];   // 32 KB: A[128][64] | B[128][64]
  const int tid = threadIdx.x, lane = tid & 63, wave = tid >> 6;
  const int wm = wave >> 1, wn = wave & 1;
  const int l16 = lane & 15, lg = lane >> 4;

  int id = blockIdx.x;
  id = (id & 7) * (nblk >> 3) + (id >> 3);
  const int row0 = (id & 127) << 7;
  const int col0 = (id >> 7) << 7;
  const int NT = K >> 6;

  const char* Ab = (const char*)A;
  const char* Bb = (const char*)Bt;
  unsigned oA[4], oB[4];
  {
    const int lr = tid >> 3;
    const int lc = tid & 7;
#pragma unroll
    for (int it = 0; it < 4; ++it) {
      const int r = it * 32 + lr;
      const int gc = ((lc ^ (r & 7)) << 3);
      oA[it] = (unsigned)(((row0 + r) * lda + gc) * 2);
      oB[it] = (unsigned)(((col0 + r) * K   + gc) * 2);
    }
  }

#define STAGE64() do { \
    gload_lds16((const bf16*)(Ab + oA[0]), lds         + tid * 8); \
    gload_lds16((const bf16*)(Ab + oA[1]), lds + 2048  + tid * 8); \
    gload_lds16((const bf16*)(Ab + oA[2]), lds + 4096  + tid * 8); \
    gload_lds16((const bf16*)(Ab + oA[3]), lds + 6144  + tid * 8); \
    gload_lds16((const bf16*)(Bb + oB[0]), lds + 8192  + tid * 8); \
    gload_lds16((const bf16*)(Bb + oB[1]), lds + 10240 + tid * 8); \
    gload_lds16((const bf16*)(Bb + oB[2]), lds + 12288 + tid * 8); \
    gload_lds16((const bf16*)(Bb + oB[3]), lds + 14336 + tid * 8); \
    oA[0] += 128; oA[1] += 128; oA[2] += 128; oA[3] += 128; \
    oB[0] += 128; oB[1] += 128; oB[2] += 128; oB[3] += 128; } while (0)

  int aoff[4][2], boff[4][2];
#pragma unroll
  for (int i = 0; i < 4; ++i) {
    const int ra = wm * 64 + i * 16 + l16;
    const int rb = wn * 64 + i * 16 + l16;
#pragma unroll
    for (int kk = 0; kk < 2; ++kk) {
      aoff[i][kk] = ra * 64 + (((kk * 4 + lg) ^ (ra & 7)) << 3);
      boff[i][kk] = 8192 + rb * 64 + (((kk * 4 + lg) ^ (rb & 7)) << 3);
    }
  }

  f32x4 acc[4][4] = {};

  STAGE64();
  for (int t = 0; t < NT; ++t) {
    __syncthreads();
    bf16x8 af[4][2];
#pragma unroll
    for (int i = 0; i < 4; ++i) {
      af[i][0] = *(const bf16x8*)&lds[aoff[i][0]];
      af[i][1] = *(const bf16x8*)&lds[aoff[i][1]];
    }
#pragma unroll
    for (int j = 0; j < 4; ++j) {
      bf16x8 b0 = *(const bf16x8*)&lds[boff[j][0]];
      bf16x8 b1 = *(const bf16x8*)&lds[boff[j][1]];
#pragma unroll
      for (int i = 0; i < 4; ++i) {
        acc[i][j] = __builtin_amdgcn_mfma_f32_16x16x32_bf16(af[i][0], b0, acc[i][j], 0, 0, 0);
        acc[i][j] = __builtin_amdgcn_mfma_f32_16x16x32_bf16(af[i][1], b1, acc[i][j], 0, 0, 0);
      }
    }
    __syncthreads();
    if (t + 1 < NT) STAGE64();
  }

#pragma unroll
  for (int i = 0; i < 4; ++i) {
    const int m0 = row0 + wm * 64 + i * 16 + lg * 4;
#pragma unroll
    for (int j = 0; j < 4; ++j) {
      const int n = col0 + wn * 64 + j * 16 + l16;
      const float bv = bias[n];
#pragma unroll
      for (int r = 0; r < 4; ++r) {
        const long m = m0 + r;
        float v = acc[i][j][r] + bv;
        if constexpr (EPI == 0) {
          ((bf16*)Cout)[m * ldc + n] = (bf16)v;
        } else if constexpr (EPI == 1) {
          ((float*)Cout)[m * ldc + n] = v + res[m * ldres + n];
        } else {
          ((bf16*)Cout)[m * ldc + n] = (bf16)fast_gelu(v);
        }
      }
    }
  }
}

// ============ kernel B: 128x128, BK=32 dbuf counted vmcnt; TILED-swizzled inputs ======
// A and Bt are in the [blk128][kblk32][128][32] pre-swizzled layout -> staging is a
// linear 8KB copy (128B source beats, no DMA-write bank conflicts); reads use the
// baked-in swizzle (conflict-free, audited over the full 64-lane window).
template<int EPI>
__global__ __launch_bounds__(256, 4)
void gemm32c(const bf16* __restrict__ A,
             const bf16* __restrict__ Bt,
             const float* __restrict__ bias,
             const float* res, int ldres,
             void* Cout, int ldc, int K, int nblk)
{
  __shared__ __align__(16) bf16 lds[16384];   // 32 KB: two 16KB tile buffers
  const int tid = threadIdx.x, lane = tid & 63, wave = tid >> 6;
  const int wm = wave >> 1, wn = wave & 1;
  const int l16 = lane & 15, lg = lane >> 4;

  int id = blockIdx.x;
  id = (id & 7) * (nblk >> 3) + (id >> 3);
  const int row0 = (id & 127) << 7;
  const int col0 = (id >> 7) << 7;
  const int NT = K >> 5;
  const int KB = K >> 5;

  const char* Ab = (const char*)A;
  const char* Bb = (const char*)Bt;
  unsigned oA = (unsigned)(((size_t)(row0 >> 7) * KB) * 8192) + tid * 16;
  unsigned oB = (unsigned)(((size_t)(col0 >> 7) * KB) * 8192) + tid * 16;

#define STAGE32(BASE) do { \
    gload_lds16((const bf16*)(Ab + oA),        lds + (BASE)        + tid * 8); \
    gload_lds16((const bf16*)(Ab + oA + 4096), lds + (BASE) + 2048 + tid * 8); \
    gload_lds16((const bf16*)(Bb + oB),        lds + (BASE) + 4096 + tid * 8); \
    gload_lds16((const bf16*)(Bb + oB + 4096), lds + (BASE) + 6144 + tid * 8); \
    oA += 8192; oB += 8192; } while (0)

  int aoff[4], boff[4];
#pragma unroll
  for (int i = 0; i < 4; ++i) {
    const int ra = wm * 64 + i * 16 + l16;
    const int rb = wn * 64 + i * 16 + l16;
    aoff[i] = ra * 32 + ((lg ^ (ra & 3) ^ ((ra >> 2) & 3)) << 3);
    boff[i] = 4096 + rb * 32 + ((lg ^ (rb & 3) ^ ((rb >> 2) & 3)) << 3);
  }

  f32x4 acc[4][4] = {};

#define TILE32(BASE, TI) do { \
    bf16x8 af[4], bfr[4]; \
    _Pragma("unroll") \
    for (int i = 0; i < 4; ++i) { \
      af[i]  = *(const bf16x8*)&lds[(BASE) + aoff[i]]; \
      bfr[i] = *(const bf16x8*)&lds[(BASE) + boff[i]]; \
    } \
    _Pragma("unroll") \
    for (int j = 0; j < 4; ++j) \
      _Pragma("unroll") \
      for (int i = 0; i < 4; ++i) \
        acc[i][j] = __builtin_amdgcn_mfma_f32_16x16x32_bf16(af[i], bfr[j], acc[i][j], 0, 0, 0); \
    LGKM0(); SB0(); \
    BAR(); \
    if ((TI) + 2 < NT) { STAGE32(BASE); VMW(4); } \
    else { VMW(0); } \
    BAR(); } while (0)

  STAGE32(0);
  STAGE32(8192);
  VMW(4);
  BAR();

  for (int t = 0; t < NT; t += 2) {
    TILE32(0, t);
    TILE32(8192, t + 1);
  }

#pragma unroll
  for (int i = 0; i < 4; ++i) {
    const int m0 = row0 + wm * 64 + i * 16 + lg * 4;
#pragma unroll
    for (int j = 0; j < 4; ++j) {
      const int n = col0 + wn * 64 + j * 16 + l16;
      const float bv = bias[n];
#pragma unroll
      for (int r = 0; r < 4; ++r) {
        const long m = m0 + r;
        float v = acc[i][j][r] + bv;
        if constexpr (EPI == 0) {
          ((bf16*)Cout)[m * ldc + n] = (bf16)v;
        } else if constexpr (EPI == 1) {
          ((float*)Cout)[m * ldc + n] = v + res[m * ldres + n];
        } else {
          ((bf16*)Cout)[m * ldc + n] = (bf16)fast_gelu(v);
        }
      }
    }
  }
}

// ---------------- dilated attention: 4 heads per block (one per wave) -----------------
__global__ __launch_bounds__(256)
void attn_kernel(bf16* qkv)
{
  __shared__ bf16 PldsA[4 * 32 * 32];
  __shared__ bf16 vTA[4 * 64 * 32];
  const int wave = threadIdx.x >> 6;
  const int lane = threadIdx.x & 63;
  bf16* Plds = PldsA + wave * 1024;
  bf16* vT   = vTA   + wave * 2048;
  const int blk = blockIdx.x * 4 + wave;
  const int h = blk & 15;
  const int g = (blk >> 4) & 63;
  const int b = blk >> 10;
  const int par = h & 1;
  const int l16 = lane & 15, lg = lane >> 4;
  const long base = ((long)b * 4096 + g * 64) * NQKV;

  bf16x8 qf[2][2], kf[2][2];
#pragma unroll
  for (int mb = 0; mb < 2; ++mb) {
    const int s = par + 2 * (mb * 16 + l16);
    const bf16* qrow = qkv + base + (long)s * NQKV + h * 64;
#pragma unroll
    for (int kk = 0; kk < 2; ++kk) {
      qf[mb][kk] = *(const bf16x8*)(qrow + kk * 32 + lg * 8);
      kf[mb][kk] = *(const bf16x8*)(qrow + 1024 + kk * 32 + lg * 8);
    }
  }

#pragma unroll
  for (int it = 0; it < 4; ++it) {
    const int kr  = it * 8 + (lane >> 3);
    const int dh0 = (lane & 7) * 8;
    const int s = par + 2 * kr;
    union { uint4 u; bf16 e[8]; } vv;
    vv.u = *(const uint4*)(qkv + base + (long)s * NQKV + 2048 + h * 64 + dh0);
#pragma unroll
    for (int j = 0; j < 8; ++j)
      vT[(dh0 + j) * 32 + kr] = vv.e[j];
  }

  f32x4 sc[2][2] = {};
#pragma unroll
  for (int mb = 0; mb < 2; ++mb)
#pragma unroll
    for (int nb = 0; nb < 2; ++nb)
#pragma unroll
      for (int kk = 0; kk < 2; ++kk)
        sc[mb][nb] = __builtin_amdgcn_mfma_f32_16x16x32_bf16(qf[mb][kk], kf[nb][kk], sc[mb][nb], 0, 0, 0);

  float pr[2][2][4];
#pragma unroll
  for (int mb = 0; mb < 2; ++mb)
#pragma unroll
    for (int r = 0; r < 4; ++r) {
      float a0 = sc[mb][0][r] * 0.125f, a1 = sc[mb][1][r] * 0.125f;
      float mx = fmaxf(a0, a1);
#pragma unroll
      for (int msk = 8; msk >= 1; msk >>= 1) mx = fmaxf(mx, __shfl_xor(mx, msk));
      float e0 = expf(a0 - mx), e1 = expf(a1 - mx);
      float sm = e0 + e1;
#pragma unroll
      for (int msk = 8; msk >= 1; msk >>= 1) sm += __shfl_xor(sm, msk);
      float inv = 1.0f / sm;
      pr[mb][0][r] = e0 * inv;
      pr[mb][1][r] = e1 * inv;
    }

  __syncthreads();
#pragma unroll
  for (int mb = 0; mb < 2; ++mb)
#pragma unroll
    for (int nb = 0; nb < 2; ++nb)
#pragma unroll
      for (int r = 0; r < 4; ++r)
        Plds[(mb * 16 + lg * 4 + r) * 32 + nb * 16 + l16] = (bf16)pr[mb][nb][r];
  __syncthreads();

  bf16x8 pa[2], vb[4];
#pragma unroll
  for (int mb = 0; mb < 2; ++mb)
    pa[mb] = *(const bf16x8*)&Plds[(mb * 16 + l16) * 32 + lg * 8];
#pragma unroll
  for (int nb = 0; nb < 4; ++nb)
    vb[nb] = *(const bf16x8*)&vT[(nb * 16 + l16) * 32 + lg * 8];
  f32x4 oc[2][4] = {};
#pragma unroll
  for (int mb = 0; mb < 2; ++mb)
#pragma unroll
    for (int nb = 0; nb < 4; ++nb)
      oc[mb][nb] = __builtin_amdgcn_mfma_f32_16x16x32_bf16(pa[mb], vb[nb], oc[mb][nb], 0, 0, 0);

#pragma unroll
  for (int mb = 0; mb < 2; ++mb)
#pragma unroll
    for (int nb = 0; nb < 4; ++nb)
#pragma unroll
      for (int r = 0; r < 4; ++r) {
        const int m = mb * 16 + lg * 4 + r;
        const int s = par + 2 * m;
        qkv[base + (long)s * NQKV + h * 64 + nb * 16 + l16] = (bf16)oc[mb][nb][r];
      }
  const uint4 z = make_uint4(0, 0, 0, 0);
#pragma unroll
  for (int it = 0; it < 4; ++it) {
    const int r2 = it * 8 + (lane >> 3);
    const int s = (1 - par) + 2 * r2;
    *(uint4*)(qkv + base + (long)s * NQKV + h * 64 + (lane & 7) * 8) = z;
  }
}

// ---------------- host-side orchestration --------------------------------------------
extern "C" void kernel_launch(void* const* d_in, const int* in_sizes, int n_in,
                              void* d_out, int out_size, void* d_ws, size_t ws_size,
                              hipStream_t stream)
{
  const float* x     = (const float*)d_in[0];
  const float* gamma = (const float*)d_in[1];
  const float* wq = (const float*)d_in[2];  const float* bq = (const float*)d_in[3];
  const float* wk = (const float*)d_in[4];  const float* bk = (const float*)d_in[5];
  const float* wv = (const float*)d_in[6];  const float* bv = (const float*)d_in[7];
  const float* wo = (const float*)d_in[8];  const float* bo = (const float*)d_in[9];
  const float* ffg = (const float*)d_in[10]; const float* ffb = (const float*)d_in[11];
  const float* w1 = (const float*)d_in[12]; const float* b1 = (const float*)d_in[13];
  const float* w2 = (const float*)d_in[14]; const float* b2 = (const float*)d_in[15];

  char* p = (char*)d_ws;
  bf16* Wqkv_t = (bf16*)p; p += (size_t)NQKV * DM * 2;   // tiled-swizzled
  bf16* Wo_t   = (bf16*)p; p += (size_t)DM * DM * 2;     // row-major
  bf16* W1_t   = (bf16*)p; p += (size_t)DFF * DM * 2;    // tiled-swizzled
  bf16* W2_t   = (bf16*)p; p += (size_t)DM * DFF * 2;    // row-major
  float* bqkv  = (float*)p; p += (size_t)NQKV * 4;
  bf16* hbuf   = (bf16*)p; p += (size_t)NTOK * DM * 2;   // tiled-swizzled
  bf16* qkv    = (bf16*)p; p += (size_t)NTOK * DFF * 2;  // row-major
  float* xnew  = (float*)d_out;

  dim3 b256(256);
  transpose_cvt_tiled<<<dim3(32, 32, 3),  b256, 0, stream>>>(wq, wk, wv, Wqkv_t, DM, DM);
  transpose_cvt      <<<dim3(32, 32),     b256, 0, stream>>>(wo, Wo_t, DM, DM);
  transpose_cvt_tiled<<<dim3(128, 32, 1), b256, 0, stream>>>(w1, w1, w1, W1_t, DM, DFF);
  transpose_cvt      <<<dim3(32, 128),    b256, 0, stream>>>(w2, W2_t, DFF, DM);
  concat_bias<<<12, b256, 0, stream>>>(bq, bk, bv, bqkv);

  ln1_kernel<<<NTOK, b256, 0, stream>>>(x, gamma, hbuf);

  // QKV GEMM (K=1024, tiled BK=32 counted): h @ [wq|wk|wv] -> qkv bf16 [16384][3072]
  gemm32c<0><<<dim3(128 * 24), b256, 0, stream>>>(
      hbuf, Wqkv_t, bqkv, nullptr, 0, qkv, NQKV, DM, 128 * 24);

  attn_kernel<<<1024, b256, 0, stream>>>(qkv);

  // WO GEMM (K=3072, BK=64 drain) + residual -> xnew fp32 (d_out)
  gemm64d<1><<<dim3(128 * 8), b256, 0, stream>>>(
      qkv, NQKV, Wo_t, bo, x, DM, xnew, DM, DM, 128 * 8);

  ln2_kernel<<<NTOK, b256, 0, stream>>>(xnew, gamma, ffg, ffb, hbuf);

  // FFN1 + GELU (K=1024, tiled BK=32 counted) -> g1 bf16 [16384][4096]
  gemm32c<2><<<dim3(128 * 32), b256, 0, stream>>>(
      hbuf, W1_t, b1, nullptr, 0, qkv, DFF, DM, 128 * 32);

  // FFN2 (K=4096, BK=64 drain) + residual -> d_out fp32
  gemm64d<1><<<dim3(128 * 8), b256, 0, stream>>>(
      qkv, DFF, W2_t, b2, xnew, DM, (float*)d_out, DM, DFF, 128 * 8);
}

// Round 16
// 569.821 us; speedup vs baseline: 1.2566x; 1.1475x over previous
//
#include <hip/hip_runtime.h>
#include <hip/hip_bf16.h>
#include <math.h>

// Problem constants
#define NTOK 16384   // B*N = 4*4096
#define DM   1024
#define NQKV 3072
#define DFF  4096

typedef __bf16 bf16;
typedef __bf16 bf16x8 __attribute__((ext_vector_type(8)));
typedef float  f32x4  __attribute__((ext_vector_type(4)));

__device__ __forceinline__ void gload_lds16(const bf16* g, bf16* l) {
  __builtin_amdgcn_global_load_lds((const __attribute__((address_space(1))) void*)g,
                                   (__attribute__((address_space(3))) void*)l,
                                   16, 0, 0);
}

#define BAR()    asm volatile("s_barrier" ::: "memory")
#define SB0()    __builtin_amdgcn_sched_barrier(0)
#define LGKM0()  asm volatile("s_waitcnt lgkmcnt(0)" ::: "memory")
#define VMW(N)   asm volatile("s_waitcnt vmcnt(" #N ")" ::: "memory")

__device__ __forceinline__ float fast_gelu(float v) {
  const float u  = 0.79788456080286536f * (v + 0.044715f * v * v * v);
  const float e  = __expf(2.0f * u);
  const float th = 1.0f - 2.0f / (e + 1.0f);
  return 0.5f * v * (1.0f + th);
}

// Grouped block mapping (shared by both GEMMs): XCD-contiguous chunk, then groups of
// 8 row-blocks with col-fastest sweep -> 2MB A-panels stay L2-resident across all cols.
__device__ __forceinline__ void map_block(int nblk, int& row0, int& col0) {
  int id = blockIdx.x;
  id = (id & 7) * (nblk >> 3) + (id >> 3);
  const int ncol = nblk >> 7;        // N/128 (M is always 16384 -> 128 row blocks)
  const int gsz  = ncol << 3;        // ids per group (8 rowblocks x ncol)
  const int grp  = id / gsz;
  const int rem  = id - grp * gsz;
  row0 = ((grp << 3) + (rem & 7)) << 7;
  col0 = (rem >> 3) << 7;
}

// Tiled-swizzled layout for gemm32c operands: [blk128][kblk32][128][32] bf16, 8KB/tile;
// within a tile row r, granule slot s holds source granule s ^ (r&3) ^ ((r>>2)&3).
__device__ __forceinline__ size_t tile_off(int rowg, int k, int KB) {
  const int rr = rowg & 127;
  const int swz = (rr & 3) ^ ((rr >> 2) & 3);
  const int slot = ((k >> 3) & 3) ^ swz;
  return ((size_t)(rowg >> 7) * KB + (k >> 5)) * 4096 + rr * 32 + slot * 8 + (k & 7);
}

// ---------------- weight transpose (row-major out): src[K][N] fp32 -> dst[N][K] bf16 --
__global__ __launch_bounds__(256)
void transpose_cvt(const float* __restrict__ src, bf16* __restrict__ dst, int K, int N)
{
  __shared__ float t[32][33];
  const int tx = threadIdx.x & 31, ty = threadIdx.x >> 5;
  const int n0 = blockIdx.x * 32, k0 = blockIdx.y * 32;
#pragma unroll
  for (int i = 0; i < 4; ++i)
    t[ty + 8*i][tx] = src[(size_t)(k0 + ty + 8*i) * N + n0 + tx];
  __syncthreads();
#pragma unroll
  for (int i = 0; i < 4; ++i)
    dst[(size_t)(n0 + ty + 8*i) * K + k0 + tx] = (bf16)t[tx][ty + 8*i];
}

// ---------------- weight transpose (tiled-swizzled out) -------------------------------
__global__ __launch_bounds__(256)
void transpose_cvt_tiled(const float* __restrict__ s0, const float* __restrict__ s1,
                         const float* __restrict__ s2, bf16* __restrict__ dst,
                         int K, int Nper)
{
  __shared__ float t[32][33];
  const int tx = threadIdx.x & 31, ty = threadIdx.x >> 5;
  const int n0 = blockIdx.x * 32, k0 = blockIdx.y * 32;
  const int z = blockIdx.z;
  const float* src = (z == 0) ? s0 : (z == 1) ? s1 : s2;
  const int KB = K >> 5;
#pragma unroll
  for (int i = 0; i < 4; ++i)
    t[ty + 8*i][tx] = src[(size_t)(k0 + ty + 8*i) * Nper + n0 + tx];
  __syncthreads();
#pragma unroll
  for (int i = 0; i < 4; ++i) {
    const int ng = z * Nper + n0 + ty + 8*i;
    dst[tile_off(ng, k0 + tx, KB)] = (bf16)t[tx][ty + 8*i];
  }
}

__global__ void concat_bias(const float* __restrict__ bq, const float* __restrict__ bk,
                            const float* __restrict__ bv, float* __restrict__ o)
{
  int i = blockIdx.x * 256 + threadIdx.x;
  o[i] = (i < 1024) ? bq[i] : (i < 2048 ? bk[i - 1024] : bv[i - 2048]);
}

// ---------------- LayerNorm 1: x fp32 -> h bf16 (tiled-swizzled) ----------------------
__global__ __launch_bounds__(256)
void ln1_kernel(const float* __restrict__ x, const float* __restrict__ gamma,
                bf16* __restrict__ out)
{
  __shared__ float2 red[4];
  const int row = blockIdx.x, tid = threadIdx.x;
  const float4 v = ((const float4*)(x + (size_t)row * DM))[tid];
  float s  = v.x + v.y + v.z + v.w;
  float s2 = v.x*v.x + v.y*v.y + v.z*v.z + v.w*v.w;
#pragma unroll
  for (int m = 32; m >= 1; m >>= 1) { s += __shfl_xor(s, m); s2 += __shfl_xor(s2, m); }
  if ((tid & 63) == 0) red[tid >> 6] = make_float2(s, s2);
  __syncthreads();
  float S  = red[0].x + red[1].x + red[2].x + red[3].x;
  float S2 = red[0].y + red[1].y + red[2].y + red[3].y;
  const float mean = S * (1.0f / DM);
  const float var  = S2 * (1.0f / DM) - mean * mean;
  const float rs   = rsqrtf(var + 1e-5f);
  const float4 g = ((const float4*)gamma)[tid];
  union { bf16 b[4]; uint2 u; } o;
  o.b[0] = (bf16)((v.x - mean) * rs * g.x);
  o.b[1] = (bf16)((v.y - mean) * rs * g.y);
  o.b[2] = (bf16)((v.z - mean) * rs * g.z);
  o.b[3] = (bf16)((v.w - mean) * rs * g.w);
  *(uint2*)(out + tile_off(row, tid * 4, DM >> 5)) = o.u;
}

// ---------------- LayerNorm 2 (double LN): xnew fp32 -> h2 bf16 (tiled-swizzled) ------
__global__ __launch_bounds__(256)
void ln2_kernel(const float* __restrict__ x, const float* __restrict__ gamma,
                const float* __restrict__ ffg, const float* __restrict__ ffb,
                bf16* __restrict__ out)
{
  __shared__ float2 red[4];
  const int row = blockIdx.x, tid = threadIdx.x;
  const float4 v = ((const float4*)(x + (size_t)row * DM))[tid];
  float s  = v.x + v.y + v.z + v.w;
  float s2 = v.x*v.x + v.y*v.y + v.z*v.z + v.w*v.w;
#pragma unroll
  for (int m = 32; m >= 1; m >>= 1) { s += __shfl_xor(s, m); s2 += __shfl_xor(s2, m); }
  if ((tid & 63) == 0) red[tid >> 6] = make_float2(s, s2);
  __syncthreads();
  float S  = red[0].x + red[1].x + red[2].x + red[3].x;
  float S2 = red[0].y + red[1].y + red[2].y + red[3].y;
  float mean = S * (1.0f / DM);
  float var  = S2 * (1.0f / DM) - mean * mean;
  float rs   = rsqrtf(var + 1e-5f);
  const float4 g = ((const float4*)ffg)[tid];
  const float4 gg = ((const float4*)gamma)[tid];
  float y0 = (v.x - mean) * rs * gg.x;
  float y1 = (v.y - mean) * rs * gg.y;
  float y2 = (v.z - mean) * rs * gg.z;
  float y3 = (v.w - mean) * rs * gg.w;
  __syncthreads();  // red[] reuse
  s  = y0 + y1 + y2 + y3;
  s2 = y0*y0 + y1*y1 + y2*y2 + y3*y3;
#pragma unroll
  for (int m = 32; m >= 1; m >>= 1) { s += __shfl_xor(s, m); s2 += __shfl_xor(s2, m); }
  if ((tid & 63) == 0) red[tid >> 6] = make_float2(s, s2);
  __syncthreads();
  S  = red[0].x + red[1].x + red[2].x + red[3].x;
  S2 = red[0].y + red[1].y + red[2].y + red[3].y;
  mean = S * (1.0f / DM);
  var  = S2 * (1.0f / DM) - mean * mean;
  rs   = rsqrtf(var + 1e-5f);
  const float4 bb = ((const float4*)ffb)[tid];
  union { bf16 b[4]; uint2 u; } o;
  o.b[0] = (bf16)((y0 - mean) * rs * g.x + bb.x);
  o.b[1] = (bf16)((y1 - mean) * rs * g.y + bb.y);
  o.b[2] = (bf16)((y2 - mean) * rs * g.z + bb.z);
  o.b[3] = (bf16)((y3 - mean) * rs * g.w + bb.w);
  *(uint2*)(out + tile_off(row, tid * 4, DM >> 5)) = o.u;
}

// ============ kernel A: 128x128, BK=64, single 32KB buffer, drain (K-deep) ============
template<int EPI>
__global__ __launch_bounds__(256, 4)
void gemm64d(const bf16* __restrict__ A, int lda,
             const bf16* __restrict__ Bt,
             const float* __restrict__ bias,
             const float* res, int ldres,
             void* Cout, int ldc, int K, int nblk)
{
  __shared__ __align__(16) bf16 lds[16384];   // 32 KB: A[128][64] | B[128][64]
  const int tid = threadIdx.x, lane = tid & 63, wave = tid >> 6;
  const int wm = wave >> 1, wn = wave & 1;
  const int l16 = lane & 15, lg = lane >> 4;

  int row0, col0;
  map_block(nblk, row0, col0);
  const int NT = K >> 6;

  const char* Ab = (const char*)A;
  const char* Bb = (const char*)Bt;
  unsigned oA[4], oB[4];
  {
    const int lr = tid >> 3;
    const int lc = tid & 7;
#pragma unroll
    for (int it = 0; it < 4; ++it) {
      const int r = it * 32 + lr;
      const int gc = ((lc ^ (r & 7)) << 3);
      oA[it] = (unsigned)(((row0 + r) * lda + gc) * 2);
      oB[it] = (unsigned)(((col0 + r) * K   + gc) * 2);
    }
  }

#define STAGE64() do { \
    gload_lds16((const bf16*)(Ab + oA[0]), lds         + tid * 8); \
    gload_lds16((const bf16*)(Ab + oA[1]), lds + 2048  + tid * 8); \
    gload_lds16((const bf16*)(Ab + oA[2]), lds + 4096  + tid * 8); \
    gload_lds16((const bf16*)(Ab + oA[3]), lds + 6144  + tid * 8); \
    gload_lds16((const bf16*)(Bb + oB[0]), lds + 8192  + tid * 8); \
    gload_lds16((const bf16*)(Bb + oB[1]), lds + 10240 + tid * 8); \
    gload_lds16((const bf16*)(Bb + oB[2]), lds + 12288 + tid * 8); \
    gload_lds16((const bf16*)(Bb + oB[3]), lds + 14336 + tid * 8); \
    oA[0] += 128; oA[1] += 128; oA[2] += 128; oA[3] += 128; \
    oB[0] += 128; oB[1] += 128; oB[2] += 128; oB[3] += 128; } while (0)

  int aoff[4][2], boff[4][2];
#pragma unroll
  for (int i = 0; i < 4; ++i) {
    const int ra = wm * 64 + i * 16 + l16;
    const int rb = wn * 64 + i * 16 + l16;
#pragma unroll
    for (int kk = 0; kk < 2; ++kk) {
      aoff[i][kk] = ra * 64 + (((kk * 4 + lg) ^ (ra & 7)) << 3);
      boff[i][kk] = 8192 + rb * 64 + (((kk * 4 + lg) ^ (rb & 7)) << 3);
    }
  }

  f32x4 acc[4][4] = {};

  STAGE64();
  for (int t = 0; t < NT; ++t) {
    __syncthreads();
    bf16x8 af[4][2];
#pragma unroll
    for (int i = 0; i < 4; ++i) {
      af[i][0] = *(const bf16x8*)&lds[aoff[i][0]];
      af[i][1] = *(const bf16x8*)&lds[aoff[i][1]];
    }
#pragma unroll
    for (int j = 0; j < 4; ++j) {
      bf16x8 b0 = *(const bf16x8*)&lds[boff[j][0]];
      bf16x8 b1 = *(const bf16x8*)&lds[boff[j][1]];
#pragma unroll
      for (int i = 0; i < 4; ++i) {
        acc[i][j] = __builtin_amdgcn_mfma_f32_16x16x32_bf16(af[i][0], b0, acc[i][j], 0, 0, 0);
        acc[i][j] = __builtin_amdgcn_mfma_f32_16x16x32_bf16(af[i][1], b1, acc[i][j], 0, 0, 0);
      }
    }
    __syncthreads();
    if (t + 1 < NT) STAGE64();
  }

#pragma unroll
  for (int i = 0; i < 4; ++i) {
    const int m0 = row0 + wm * 64 + i * 16 + lg * 4;
#pragma unroll
    for (int j = 0; j < 4; ++j) {
      const int n = col0 + wn * 64 + j * 16 + l16;
      const float bv = bias[n];
#pragma unroll
      for (int r = 0; r < 4; ++r) {
        const long m = m0 + r;
        float v = acc[i][j][r] + bv;
        if constexpr (EPI == 0) {
          ((bf16*)Cout)[m * ldc + n] = (bf16)v;
        } else if constexpr (EPI == 1) {
          ((float*)Cout)[m * ldc + n] = v + res[m * ldres + n];
        } else {
          ((bf16*)Cout)[m * ldc + n] = (bf16)fast_gelu(v);
        }
      }
    }
  }
}

// ============ kernel B: 128x128, BK=32 dbuf counted vmcnt; TILED-swizzled inputs ======
template<int EPI>
__global__ __launch_bounds__(256, 4)
void gemm32c(const bf16* __restrict__ A,
             const bf16* __restrict__ Bt,
             const float* __restrict__ bias,
             const float* res, int ldres,
             void* Cout, int ldc, int K, int nblk)
{
  __shared__ __align__(16) bf16 lds[16384];   // 32 KB: two 16KB tile buffers
  const int tid = threadIdx.x, lane = tid & 63, wave = tid >> 6;
  const int wm = wave >> 1, wn = wave & 1;
  const int l16 = lane & 15, lg = lane >> 4;

  int row0, col0;
  map_block(nblk, row0, col0);
  const int NT = K >> 5;
  const int KB = K >> 5;

  const char* Ab = (const char*)A;
  const char* Bb = (const char*)Bt;
  unsigned oA = (unsigned)(((size_t)(row0 >> 7) * KB) * 8192) + tid * 16;
  unsigned oB = (unsigned)(((size_t)(col0 >> 7) * KB) * 8192) + tid * 16;

#define STAGE32(BASE) do { \
    gload_lds16((const bf16*)(Ab + oA),        lds + (BASE)        + tid * 8); \
    gload_lds16((const bf16*)(Ab + oA + 4096), lds + (BASE) + 2048 + tid * 8); \
    gload_lds16((const bf16*)(Bb + oB),        lds + (BASE) + 4096 + tid * 8); \
    gload_lds16((const bf16*)(Bb + oB + 4096), lds + (BASE) + 6144 + tid * 8); \
    oA += 8192; oB += 8192; } while (0)

  int aoff[4], boff[4];
#pragma unroll
  for (int i = 0; i < 4; ++i) {
    const int ra = wm * 64 + i * 16 + l16;
    const int rb = wn * 64 + i * 16 + l16;
    aoff[i] = ra * 32 + ((lg ^ (ra & 3) ^ ((ra >> 2) & 3)) << 3);
    boff[i] = 4096 + rb * 32 + ((lg ^ (rb & 3) ^ ((rb >> 2) & 3)) << 3);
  }

  f32x4 acc[4][4] = {};

#define TILE32(BASE, TI) do { \
    bf16x8 af[4], bfr[4]; \
    _Pragma("unroll") \
    for (int i = 0; i < 4; ++i) { \
      af[i]  = *(const bf16x8*)&lds[(BASE) + aoff[i]]; \
      bfr[i] = *(const bf16x8*)&lds[(BASE) + boff[i]]; \
    } \
    _Pragma("unroll") \
    for (int j = 0; j < 4; ++j) \
      _Pragma("unroll") \
      for (int i = 0; i < 4; ++i) \
        acc[i][j] = __builtin_amdgcn_mfma_f32_16x16x32_bf16(af[i], bfr[j], acc[i][j], 0, 0, 0); \
    LGKM0(); SB0(); \
    BAR(); \
    if ((TI) + 2 < NT) { STAGE32(BASE); VMW(4); } \
    else { VMW(0); } \
    BAR(); } while (0)

  STAGE32(0);
  STAGE32(8192);
  VMW(4);
  BAR();

  for (int t = 0; t < NT; t += 2) {
    TILE32(0, t);
    TILE32(8192, t + 1);
  }

#pragma unroll
  for (int i = 0; i < 4; ++i) {
    const int m0 = row0 + wm * 64 + i * 16 + lg * 4;
#pragma unroll
    for (int j = 0; j < 4; ++j) {
      const int n = col0 + wn * 64 + j * 16 + l16;
      const float bv = bias[n];
#pragma unroll
      for (int r = 0; r < 4; ++r) {
        const long m = m0 + r;
        float v = acc[i][j][r] + bv;
        if constexpr (EPI == 0) {
          ((bf16*)Cout)[m * ldc + n] = (bf16)v;
        } else if constexpr (EPI == 1) {
          ((float*)Cout)[m * ldc + n] = v + res[m * ldres + n];
        } else {
          ((bf16*)Cout)[m * ldc + n] = (bf16)fast_gelu(v);
        }
      }
    }
  }
}

// ---------------- dilated attention: 4 heads per block (one per wave) -----------------
__global__ __launch_bounds__(256)
void attn_kernel(bf16* qkv)
{
  __shared__ bf16 PldsA[4 * 32 * 32];
  __shared__ bf16 vTA[4 * 64 * 32];
  const int wave = threadIdx.x >> 6;
  const int lane = threadIdx.x & 63;
  bf16* Plds = PldsA + wave * 1024;
  bf16* vT   = vTA   + wave * 2048;
  const int blk = blockIdx.x * 4 + wave;
  const int h = blk & 15;
  const int g = (blk >> 4) & 63;
  const int b = blk >> 10;
  const int par = h & 1;
  const int l16 = lane & 15, lg = lane >> 4;
  const long base = ((long)b * 4096 + g * 64) * NQKV;

  bf16x8 qf[2][2], kf[2][2];
#pragma unroll
  for (int mb = 0; mb < 2; ++mb) {
    const int s = par + 2 * (mb * 16 + l16);
    const bf16* qrow = qkv + base + (long)s * NQKV + h * 64;
#pragma unroll
    for (int kk = 0; kk < 2; ++kk) {
      qf[mb][kk] = *(const bf16x8*)(qrow + kk * 32 + lg * 8);
      kf[mb][kk] = *(const bf16x8*)(qrow + 1024 + kk * 32 + lg * 8);
    }
  }

#pragma unroll
  for (int it = 0; it < 4; ++it) {
    const int kr  = it * 8 + (lane >> 3);
    const int dh0 = (lane & 7) * 8;
    const int s = par + 2 * kr;
    union { uint4 u; bf16 e[8]; } vv;
    vv.u = *(const uint4*)(qkv + base + (long)s * NQKV + 2048 + h * 64 + dh0);
#pragma unroll
    for (int j = 0; j < 8; ++j)
      vT[(dh0 + j) * 32 + kr] = vv.e[j];
  }

  f32x4 sc[2][2] = {};
#pragma unroll
  for (int mb = 0; mb < 2; ++mb)
#pragma unroll
    for (int nb = 0; nb < 2; ++nb)
#pragma unroll
      for (int kk = 0; kk < 2; ++kk)
        sc[mb][nb] = __builtin_amdgcn_mfma_f32_16x16x32_bf16(qf[mb][kk], kf[nb][kk], sc[mb][nb], 0, 0, 0);

  float pr[2][2][4];
#pragma unroll
  for (int mb = 0; mb < 2; ++mb)
#pragma unroll
    for (int r = 0; r < 4; ++r) {
      float a0 = sc[mb][0][r] * 0.125f, a1 = sc[mb][1][r] * 0.125f;
      float mx = fmaxf(a0, a1);
#pragma unroll
      for (int msk = 8; msk >= 1; msk >>= 1) mx = fmaxf(mx, __shfl_xor(mx, msk));
      float e0 = expf(a0 - mx), e1 = expf(a1 - mx);
      float sm = e0 + e1;
#pragma unroll
      for (int msk = 8; msk >= 1; msk >>= 1) sm += __shfl_xor(sm, msk);
      float inv = 1.0f / sm;
      pr[mb][0][r] = e0 * inv;
      pr[mb][1][r] = e1 * inv;
    }

  __syncthreads();
#pragma unroll
  for (int mb = 0; mb < 2; ++mb)
#pragma unroll
    for (int nb = 0; nb < 2; ++nb)
#pragma unroll
      for (int r = 0; r < 4; ++r)
        Plds[(mb * 16 + lg * 4 + r) * 32 + nb * 16 + l16] = (bf16)pr[mb][nb][r];
  __syncthreads();

  bf16x8 pa[2], vb[4];
#pragma unroll
  for (int mb = 0; mb < 2; ++mb)
    pa[mb] = *(const bf16x8*)&Plds[(mb * 16 + l16) * 32 + lg * 8];
#pragma unroll
  for (int nb = 0; nb < 4; ++nb)
    vb[nb] = *(const bf16x8*)&vT[(nb * 16 + l16) * 32 + lg * 8];
  f32x4 oc[2][4] = {};
#pragma unroll
  for (int mb = 0; mb < 2; ++mb)
#pragma unroll
    for (int nb = 0; nb < 4; ++nb)
      oc[mb][nb] = __builtin_amdgcn_mfma_f32_16x16x32_bf16(pa[mb], vb[nb], oc[mb][nb], 0, 0, 0);

#pragma unroll
  for (int mb = 0; mb < 2; ++mb)
#pragma unroll
    for (int nb = 0; nb < 4; ++nb)
#pragma unroll
      for (int r = 0; r < 4; ++r) {
        const int m = mb * 16 + lg * 4 + r;
        const int s = par + 2 * m;
        qkv[base + (long)s * NQKV + h * 64 + nb * 16 + l16] = (bf16)oc[mb][nb][r];
      }
  const uint4 z = make_uint4(0, 0, 0, 0);
#pragma unroll
  for (int it = 0; it < 4; ++it) {
    const int r2 = it * 8 + (lane >> 3);
    const int s = (1 - par) + 2 * r2;
    *(uint4*)(qkv + base + (long)s * NQKV + h * 64 + (lane & 7) * 8) = z;
  }
}

// ---------------- host-side orchestration --------------------------------------------
extern "C" void kernel_launch(void* const* d_in, const int* in_sizes, int n_in,
                              void* d_out, int out_size, void* d_ws, size_t ws_size,
                              hipStream_t stream)
{
  const float* x     = (const float*)d_in[0];
  const float* gamma = (const float*)d_in[1];
  const float* wq = (const float*)d_in[2];  const float* bq = (const float*)d_in[3];
  const float* wk = (const float*)d_in[4];  const float* bk = (const float*)d_in[5];
  const float* wv = (const float*)d_in[6];  const float* bv = (const float*)d_in[7];
  const float* wo = (const float*)d_in[8];  const float* bo = (const float*)d_in[9];
  const float* ffg = (const float*)d_in[10]; const float* ffb = (const float*)d_in[11];
  const float* w1 = (const float*)d_in[12]; const float* b1 = (const float*)d_in[13];
  const float* w2 = (const float*)d_in[14]; const float* b2 = (const float*)d_in[15];

  char* p = (char*)d_ws;
  bf16* Wqkv_t = (bf16*)p; p += (size_t)NQKV * DM * 2;   // tiled-swizzled
  bf16* Wo_t   = (bf16*)p; p += (size_t)DM * DM * 2;     // row-major
  bf16* W1_t   = (bf16*)p; p += (size_t)DFF * DM * 2;    // tiled-swizzled
  bf16* W2_t   = (bf16*)p; p += (size_t)DM * DFF * 2;    // row-major
  float* bqkv  = (float*)p; p += (size_t)NQKV * 4;
  bf16* hbuf   = (bf16*)p; p += (size_t)NTOK * DM * 2;   // tiled-swizzled
  bf16* qkv    = (bf16*)p; p += (size_t)NTOK * DFF * 2;  // row-major
  float* xnew  = (float*)d_out;

  dim3 b256(256);
  transpose_cvt_tiled<<<dim3(32, 32, 3),  b256, 0, stream>>>(wq, wk, wv, Wqkv_t, DM, DM);
  transpose_cvt      <<<dim3(32, 32),     b256, 0, stream>>>(wo, Wo_t, DM, DM);
  transpose_cvt_tiled<<<dim3(128, 32, 1), b256, 0, stream>>>(w1, w1, w1, W1_t, DM, DFF);
  transpose_cvt      <<<dim3(32, 128),    b256, 0, stream>>>(w2, W2_t, DFF, DM);
  concat_bias<<<12, b256, 0, stream>>>(bq, bk, bv, bqkv);

  ln1_kernel<<<NTOK, b256, 0, stream>>>(x, gamma, hbuf);

  // QKV GEMM (K=1024, tiled BK=32 counted): h @ [wq|wk|wv] -> qkv bf16 [16384][3072]
  gemm32c<0><<<dim3(128 * 24), b256, 0, stream>>>(
      hbuf, Wqkv_t, bqkv, nullptr, 0, qkv, NQKV, DM, 128 * 24);

  attn_kernel<<<1024, b256, 0, stream>>>(qkv);

  // WO GEMM (K=1024 eff, lda=3072, BK=64 drain) + residual -> xnew fp32 (d_out)
  gemm64d<1><<<dim3(128 * 8), b256, 0, stream>>>(
      qkv, NQKV, Wo_t, bo, x, DM, xnew, DM, DM, 128 * 8);

  ln2_kernel<<<NTOK, b256, 0, stream>>>(xnew, gamma, ffg, ffb, hbuf);

  // FFN1 + GELU (K=1024, tiled BK=32 counted) -> g1 bf16 [16384][4096]
  gemm32c<2><<<dim3(128 * 32), b256, 0, stream>>>(
      hbuf, W1_t, b1, nullptr, 0, qkv, DFF, DM, 128 * 32);

  // FFN2 (K=4096, BK=64 drain) + residual -> d_out fp32
  gemm64d<1><<<dim3(128 * 8), b256, 0, stream>>>(
      qkv, DFF, W2_t, b2, xnew, DM, (float*)d_out, DM, DFF, 128 * 8);
}

// Round 17
// 552.944 us; speedup vs baseline: 1.2950x; 1.0305x over previous
//
#include <hip/hip_runtime.h>
#include <hip/hip_bf16.h>
#include <math.h>

// Problem constants
#define NTOK 16384   // B*N = 4*4096
#define DM   1024
#define NQKV 3072
#define DFF  4096

typedef __bf16 bf16;
typedef __bf16 bf16x8 __attribute__((ext_vector_type(8)));
typedef float  f32x4  __attribute__((ext_vector_type(4)));

__device__ __forceinline__ void gload_lds16(const bf16* g, bf16* l) {
  __builtin_amdgcn_global_load_lds((const __attribute__((address_space(1))) void*)g,
                                   (__attribute__((address_space(3))) void*)l,
                                   16, 0, 0);
}

#define BAR()    asm volatile("s_barrier" ::: "memory")
#define SB0()    __builtin_amdgcn_sched_barrier(0)
#define LGKM0()  asm volatile("s_waitcnt lgkmcnt(0)" ::: "memory")
#define VMW(N)   asm volatile("s_waitcnt vmcnt(" #N ")" ::: "memory")

__device__ __forceinline__ float fast_gelu(float v) {
  const float u  = 0.79788456080286536f * (v + 0.044715f * v * v * v);
  const float e  = __expf(2.0f * u);
  const float th = 1.0f - 2.0f / (e + 1.0f);
  return 0.5f * v * (1.0f + th);
}

// Grouped block mapping (shared by both GEMMs): XCD-contiguous chunk, then groups of
// 8 row-blocks with col-fastest sweep -> 2MB A-panels stay L2-resident across all cols.
__device__ __forceinline__ void map_block(int nblk, int& row0, int& col0) {
  int id = blockIdx.x;
  id = (id & 7) * (nblk >> 3) + (id >> 3);
  const int ncol = nblk >> 7;        // N/128 (M is always 16384 -> 128 row blocks)
  const int gsz  = ncol << 3;        // ids per group (8 rowblocks x ncol)
  const int grp  = id / gsz;
  const int rem  = id - grp * gsz;
  row0 = ((grp << 3) + (rem & 7)) << 7;
  col0 = (rem >> 3) << 7;
}

// Tiled-swizzled layout for gemm32c operands: [blk128][kblk32][128][32] bf16, 8KB/tile;
// within a tile row r, granule slot s holds source granule s ^ (r&3) ^ ((r>>2)&3).
__device__ __forceinline__ size_t tile_off(int rowg, int k, int KB) {
  const int rr = rowg & 127;
  const int swz = (rr & 3) ^ ((rr >> 2) & 3);
  const int slot = ((k >> 3) & 3) ^ swz;
  return ((size_t)(rowg >> 7) * KB + (k >> 5)) * 4096 + rr * 32 + slot * 8 + (k & 7);
}

// ---------------- weight transpose (row-major out): src[K][N] fp32 -> dst[N][K] bf16 --
__global__ __launch_bounds__(256)
void transpose_cvt(const float* __restrict__ src, bf16* __restrict__ dst, int K, int N)
{
  __shared__ float t[32][33];
  const int tx = threadIdx.x & 31, ty = threadIdx.x >> 5;
  const int n0 = blockIdx.x * 32, k0 = blockIdx.y * 32;
#pragma unroll
  for (int i = 0; i < 4; ++i)
    t[ty + 8*i][tx] = src[(size_t)(k0 + ty + 8*i) * N + n0 + tx];
  __syncthreads();
#pragma unroll
  for (int i = 0; i < 4; ++i)
    dst[(size_t)(n0 + ty + 8*i) * K + k0 + tx] = (bf16)t[tx][ty + 8*i];
}

// ---------------- weight transpose (tiled-swizzled out) -------------------------------
__global__ __launch_bounds__(256)
void transpose_cvt_tiled(const float* __restrict__ s0, const float* __restrict__ s1,
                         const float* __restrict__ s2, bf16* __restrict__ dst,
                         int K, int Nper)
{
  __shared__ float t[32][33];
  const int tx = threadIdx.x & 31, ty = threadIdx.x >> 5;
  const int n0 = blockIdx.x * 32, k0 = blockIdx.y * 32;
  const int z = blockIdx.z;
  const float* src = (z == 0) ? s0 : (z == 1) ? s1 : s2;
  const int KB = K >> 5;
#pragma unroll
  for (int i = 0; i < 4; ++i)
    t[ty + 8*i][tx] = src[(size_t)(k0 + ty + 8*i) * Nper + n0 + tx];
  __syncthreads();
#pragma unroll
  for (int i = 0; i < 4; ++i) {
    const int ng = z * Nper + n0 + ty + 8*i;
    dst[tile_off(ng, k0 + tx, KB)] = (bf16)t[tx][ty + 8*i];
  }
}

__global__ void concat_bias(const float* __restrict__ bq, const float* __restrict__ bk,
                            const float* __restrict__ bv, float* __restrict__ o)
{
  int i = blockIdx.x * 256 + threadIdx.x;
  o[i] = (i < 1024) ? bq[i] : (i < 2048 ? bk[i - 1024] : bv[i - 2048]);
}

// ---------------- LayerNorm 1: x fp32 -> h bf16 (tiled-swizzled) ----------------------
__global__ __launch_bounds__(256)
void ln1_kernel(const float* __restrict__ x, const float* __restrict__ gamma,
                bf16* __restrict__ out)
{
  __shared__ float2 red[4];
  const int row = blockIdx.x, tid = threadIdx.x;
  const float4 v = ((const float4*)(x + (size_t)row * DM))[tid];
  float s  = v.x + v.y + v.z + v.w;
  float s2 = v.x*v.x + v.y*v.y + v.z*v.z + v.w*v.w;
#pragma unroll
  for (int m = 32; m >= 1; m >>= 1) { s += __shfl_xor(s, m); s2 += __shfl_xor(s2, m); }
  if ((tid & 63) == 0) red[tid >> 6] = make_float2(s, s2);
  __syncthreads();
  float S  = red[0].x + red[1].x + red[2].x + red[3].x;
  float S2 = red[0].y + red[1].y + red[2].y + red[3].y;
  const float mean = S * (1.0f / DM);
  const float var  = S2 * (1.0f / DM) - mean * mean;
  const float rs   = rsqrtf(var + 1e-5f);
  const float4 g = ((const float4*)gamma)[tid];
  union { bf16 b[4]; uint2 u; } o;
  o.b[0] = (bf16)((v.x - mean) * rs * g.x);
  o.b[1] = (bf16)((v.y - mean) * rs * g.y);
  o.b[2] = (bf16)((v.z - mean) * rs * g.z);
  o.b[3] = (bf16)((v.w - mean) * rs * g.w);
  *(uint2*)(out + tile_off(row, tid * 4, DM >> 5)) = o.u;
}

// ---------------- LayerNorm 2 (double LN): xnew fp32 -> h2 bf16 (tiled-swizzled) ------
__global__ __launch_bounds__(256)
void ln2_kernel(const float* __restrict__ x, const float* __restrict__ gamma,
                const float* __restrict__ ffg, const float* __restrict__ ffb,
                bf16* __restrict__ out)
{
  __shared__ float2 red[4];
  const int row = blockIdx.x, tid = threadIdx.x;
  const float4 v = ((const float4*)(x + (size_t)row * DM))[tid];
  float s  = v.x + v.y + v.z + v.w;
  float s2 = v.x*v.x + v.y*v.y + v.z*v.z + v.w*v.w;
#pragma unroll
  for (int m = 32; m >= 1; m >>= 1) { s += __shfl_xor(s, m); s2 += __shfl_xor(s2, m); }
  if ((tid & 63) == 0) red[tid >> 6] = make_float2(s, s2);
  __syncthreads();
  float S  = red[0].x + red[1].x + red[2].x + red[3].x;
  float S2 = red[0].y + red[1].y + red[2].y + red[3].y;
  float mean = S * (1.0f / DM);
  float var  = S2 * (1.0f / DM) - mean * mean;
  float rs   = rsqrtf(var + 1e-5f);
  const float4 g = ((const float4*)ffg)[tid];
  const float4 gg = ((const float4*)gamma)[tid];
  float y0 = (v.x - mean) * rs * gg.x;
  float y1 = (v.y - mean) * rs * gg.y;
  float y2 = (v.z - mean) * rs * gg.z;
  float y3 = (v.w - mean) * rs * gg.w;
  __syncthreads();  // red[] reuse
  s  = y0 + y1 + y2 + y3;
  s2 = y0*y0 + y1*y1 + y2*y2 + y3*y3;
#pragma unroll
  for (int m = 32; m >= 1; m >>= 1) { s += __shfl_xor(s, m); s2 += __shfl_xor(s2, m); }
  if ((tid & 63) == 0) red[tid >> 6] = make_float2(s, s2);
  __syncthreads();
  S  = red[0].x + red[1].x + red[2].x + red[3].x;
  S2 = red[0].y + red[1].y + red[2].y + red[3].y;
  mean = S * (1.0f / DM);
  var  = S2 * (1.0f / DM) - mean * mean;
  rs   = rsqrtf(var + 1e-5f);
  const float4 bb = ((const float4*)ffb)[tid];
  union { bf16 b[4]; uint2 u; } o;
  o.b[0] = (bf16)((y0 - mean) * rs * g.x + bb.x);
  o.b[1] = (bf16)((y1 - mean) * rs * g.y + bb.y);
  o.b[2] = (bf16)((y2 - mean) * rs * g.z + bb.z);
  o.b[3] = (bf16)((y3 - mean) * rs * g.w + bb.w);
  *(uint2*)(out + tile_off(row, tid * 4, DM >> 5)) = o.u;
}

// ============ kernel A: 128x128, BK=64, single 32KB buffer, stage-before-MFMA =========
// r17 reorder: read frags -> MFMA(kk=0) -> read B(kk=1) -> lgkm0+BAR (reads drained)
// -> STAGE(t+1) -> MFMA(kk=1) covers DMA issue -> vmcnt(0)+BAR publishes t+1.
template<int EPI>
__global__ __launch_bounds__(256, 4)
void gemm64d(const bf16* __restrict__ A, int lda,
             const bf16* __restrict__ Bt,
             const float* __restrict__ bias,
             const float* res, int ldres,
             void* Cout, int ldc, int K, int nblk)
{
  __shared__ __align__(16) bf16 lds[16384];   // 32 KB: A[128][64] | B[128][64]
  const int tid = threadIdx.x, lane = tid & 63, wave = tid >> 6;
  const int wm = wave >> 1, wn = wave & 1;
  const int l16 = lane & 15, lg = lane >> 4;

  int row0, col0;
  map_block(nblk, row0, col0);
  const int NT = K >> 6;

  const char* Ab = (const char*)A;
  const char* Bb = (const char*)Bt;
  unsigned oA[4], oB[4];
  {
    const int lr = tid >> 3;
    const int lc = tid & 7;
#pragma unroll
    for (int it = 0; it < 4; ++it) {
      const int r = it * 32 + lr;
      const int gc = ((lc ^ (r & 7)) << 3);
      oA[it] = (unsigned)(((row0 + r) * lda + gc) * 2);
      oB[it] = (unsigned)(((col0 + r) * K   + gc) * 2);
    }
  }

#define STAGE64() do { \
    gload_lds16((const bf16*)(Ab + oA[0]), lds         + tid * 8); \
    gload_lds16((const bf16*)(Ab + oA[1]), lds + 2048  + tid * 8); \
    gload_lds16((const bf16*)(Ab + oA[2]), lds + 4096  + tid * 8); \
    gload_lds16((const bf16*)(Ab + oA[3]), lds + 6144  + tid * 8); \
    gload_lds16((const bf16*)(Bb + oB[0]), lds + 8192  + tid * 8); \
    gload_lds16((const bf16*)(Bb + oB[1]), lds + 10240 + tid * 8); \
    gload_lds16((const bf16*)(Bb + oB[2]), lds + 12288 + tid * 8); \
    gload_lds16((const bf16*)(Bb + oB[3]), lds + 14336 + tid * 8); \
    oA[0] += 128; oA[1] += 128; oA[2] += 128; oA[3] += 128; \
    oB[0] += 128; oB[1] += 128; oB[2] += 128; oB[3] += 128; } while (0)

  int aoff[4][2], boff[4][2];
#pragma unroll
  for (int i = 0; i < 4; ++i) {
    const int ra = wm * 64 + i * 16 + l16;
    const int rb = wn * 64 + i * 16 + l16;
#pragma unroll
    for (int kk = 0; kk < 2; ++kk) {
      aoff[i][kk] = ra * 64 + (((kk * 4 + lg) ^ (ra & 7)) << 3);
      boff[i][kk] = 8192 + rb * 64 + (((kk * 4 + lg) ^ (rb & 7)) << 3);
    }
  }

  f32x4 acc[4][4] = {};

  STAGE64();                 // tile 0
  VMW(0); BAR();             // tile 0 landed + published
  for (int t = 0; t < NT; ++t) {
    bf16x8 af[4][2], bf0[4];
#pragma unroll
    for (int i = 0; i < 4; ++i) {
      af[i][0] = *(const bf16x8*)&lds[aoff[i][0]];
      af[i][1] = *(const bf16x8*)&lds[aoff[i][1]];
      bf0[i]   = *(const bf16x8*)&lds[boff[i][0]];
    }
#pragma unroll
    for (int j = 0; j < 4; ++j)
#pragma unroll
      for (int i = 0; i < 4; ++i)
        acc[i][j] = __builtin_amdgcn_mfma_f32_16x16x32_bf16(af[i][0], bf0[j], acc[i][j], 0, 0, 0);
    bf16x8 bf1[4];
#pragma unroll
    for (int j = 0; j < 4; ++j)
      bf1[j] = *(const bf16x8*)&lds[boff[j][1]];
    LGKM0(); SB0();
    BAR();                   // all waves' reads of tile t drained
    if (t + 1 < NT) STAGE64();   // restage buffer with tile t+1 (DMA in flight)
#pragma unroll
    for (int j = 0; j < 4; ++j)
#pragma unroll
      for (int i = 0; i < 4; ++i)
        acc[i][j] = __builtin_amdgcn_mfma_f32_16x16x32_bf16(af[i][1], bf1[j], acc[i][j], 0, 0, 0);
    VMW(0); BAR();           // tile t+1 landed + published
  }

#pragma unroll
  for (int i = 0; i < 4; ++i) {
    const int m0 = row0 + wm * 64 + i * 16 + lg * 4;
#pragma unroll
    for (int j = 0; j < 4; ++j) {
      const int n = col0 + wn * 64 + j * 16 + l16;
      const float bv = bias[n];
#pragma unroll
      for (int r = 0; r < 4; ++r) {
        const long m = m0 + r;
        float v = acc[i][j][r] + bv;
        if constexpr (EPI == 0) {
          ((bf16*)Cout)[m * ldc + n] = (bf16)v;
        } else if constexpr (EPI == 1) {
          ((float*)Cout)[m * ldc + n] = v + res[m * ldres + n];
        } else {
          ((bf16*)Cout)[m * ldc + n] = (bf16)fast_gelu(v);
        }
      }
    }
  }
}

// ============ kernel B: 128x128, BK=32 dbuf counted vmcnt; TILED-swizzled inputs ======
template<int EPI>
__global__ __launch_bounds__(256, 4)
void gemm32c(const bf16* __restrict__ A,
             const bf16* __restrict__ Bt,
             const float* __restrict__ bias,
             const float* res, int ldres,
             void* Cout, int ldc, int K, int nblk)
{
  __shared__ __align__(16) bf16 lds[16384];   // 32 KB: two 16KB tile buffers
  const int tid = threadIdx.x, lane = tid & 63, wave = tid >> 6;
  const int wm = wave >> 1, wn = wave & 1;
  const int l16 = lane & 15, lg = lane >> 4;

  int row0, col0;
  map_block(nblk, row0, col0);
  const int NT = K >> 5;
  const int KB = K >> 5;

  const char* Ab = (const char*)A;
  const char* Bb = (const char*)Bt;
  unsigned oA = (unsigned)(((size_t)(row0 >> 7) * KB) * 8192) + tid * 16;
  unsigned oB = (unsigned)(((size_t)(col0 >> 7) * KB) * 8192) + tid * 16;

#define STAGE32(BASE) do { \
    gload_lds16((const bf16*)(Ab + oA),        lds + (BASE)        + tid * 8); \
    gload_lds16((const bf16*)(Ab + oA + 4096), lds + (BASE) + 2048 + tid * 8); \
    gload_lds16((const bf16*)(Bb + oB),        lds + (BASE) + 4096 + tid * 8); \
    gload_lds16((const bf16*)(Bb + oB + 4096), lds + (BASE) + 6144 + tid * 8); \
    oA += 8192; oB += 8192; } while (0)

  int aoff[4], boff[4];
#pragma unroll
  for (int i = 0; i < 4; ++i) {
    const int ra = wm * 64 + i * 16 + l16;
    const int rb = wn * 64 + i * 16 + l16;
    aoff[i] = ra * 32 + ((lg ^ (ra & 3) ^ ((ra >> 2) & 3)) << 3);
    boff[i] = 4096 + rb * 32 + ((lg ^ (rb & 3) ^ ((rb >> 2) & 3)) << 3);
  }

  f32x4 acc[4][4] = {};

#define TILE32(BASE, TI) do { \
    bf16x8 af[4], bfr[4]; \
    _Pragma("unroll") \
    for (int i = 0; i < 4; ++i) { \
      af[i]  = *(const bf16x8*)&lds[(BASE) + aoff[i]]; \
      bfr[i] = *(const bf16x8*)&lds[(BASE) + boff[i]]; \
    } \
    _Pragma("unroll") \
    for (int j = 0; j < 4; ++j) \
      _Pragma("unroll") \
      for (int i = 0; i < 4; ++i) \
        acc[i][j] = __builtin_amdgcn_mfma_f32_16x16x32_bf16(af[i], bfr[j], acc[i][j], 0, 0, 0); \
    LGKM0(); SB0(); \
    BAR(); \
    if ((TI) + 2 < NT) { STAGE32(BASE); VMW(4); } \
    else { VMW(0); } \
    BAR(); } while (0)

  STAGE32(0);
  STAGE32(8192);
  VMW(4);
  BAR();

  for (int t = 0; t < NT; t += 2) {
    TILE32(0, t);
    TILE32(8192, t + 1);
  }

#pragma unroll
  for (int i = 0; i < 4; ++i) {
    const int m0 = row0 + wm * 64 + i * 16 + lg * 4;
#pragma unroll
    for (int j = 0; j < 4; ++j) {
      const int n = col0 + wn * 64 + j * 16 + l16;
      const float bv = bias[n];
#pragma unroll
      for (int r = 0; r < 4; ++r) {
        const long m = m0 + r;
        float v = acc[i][j][r] + bv;
        if constexpr (EPI == 0) {
          ((bf16*)Cout)[m * ldc + n] = (bf16)v;
        } else if constexpr (EPI == 1) {
          ((float*)Cout)[m * ldc + n] = v + res[m * ldres + n];
        } else {
          ((bf16*)Cout)[m * ldc + n] = (bf16)fast_gelu(v);
        }
      }
    }
  }
}

// ---------------- dilated attention: 4 heads per block (one per wave) -----------------
__global__ __launch_bounds__(256)
void attn_kernel(bf16* qkv)
{
  __shared__ bf16 PldsA[4 * 32 * 32];
  __shared__ bf16 vTA[4 * 64 * 32];
  const int wave = threadIdx.x >> 6;
  const int lane = threadIdx.x & 63;
  bf16* Plds = PldsA + wave * 1024;
  bf16* vT   = vTA   + wave * 2048;
  const int blk = blockIdx.x * 4 + wave;
  const int h = blk & 15;
  const int g = (blk >> 4) & 63;
  const int b = blk >> 10;
  const int par = h & 1;
  const int l16 = lane & 15, lg = lane >> 4;
  const long base = ((long)b * 4096 + g * 64) * NQKV;

  bf16x8 qf[2][2], kf[2][2];
#pragma unroll
  for (int mb = 0; mb < 2; ++mb) {
    const int s = par + 2 * (mb * 16 + l16);
    const bf16* qrow = qkv + base + (long)s * NQKV + h * 64;
#pragma unroll
    for (int kk = 0; kk < 2; ++kk) {
      qf[mb][kk] = *(const bf16x8*)(qrow + kk * 32 + lg * 8);
      kf[mb][kk] = *(const bf16x8*)(qrow + 1024 + kk * 32 + lg * 8);
    }
  }

#pragma unroll
  for (int it = 0; it < 4; ++it) {
    const int kr  = it * 8 + (lane >> 3);
    const int dh0 = (lane & 7) * 8;
    const int s = par + 2 * kr;
    union { uint4 u; bf16 e[8]; } vv;
    vv.u = *(const uint4*)(qkv + base + (long)s * NQKV + 2048 + h * 64 + dh0);
#pragma unroll
    for (int j = 0; j < 8; ++j)
      vT[(dh0 + j) * 32 + kr] = vv.e[j];
  }

  f32x4 sc[2][2] = {};
#pragma unroll
  for (int mb = 0; mb < 2; ++mb)
#pragma unroll
    for (int nb = 0; nb < 2; ++nb)
#pragma unroll
      for (int kk = 0; kk < 2; ++kk)
        sc[mb][nb] = __builtin_amdgcn_mfma_f32_16x16x32_bf16(qf[mb][kk], kf[nb][kk], sc[mb][nb], 0, 0, 0);

  float pr[2][2][4];
#pragma unroll
  for (int mb = 0; mb < 2; ++mb)
#pragma unroll
    for (int r = 0; r < 4; ++r) {
      float a0 = sc[mb][0][r] * 0.125f, a1 = sc[mb][1][r] * 0.125f;
      float mx = fmaxf(a0, a1);
#pragma unroll
      for (int msk = 8; msk >= 1; msk >>= 1) mx = fmaxf(mx, __shfl_xor(mx, msk));
      float e0 = expf(a0 - mx), e1 = expf(a1 - mx);
      float sm = e0 + e1;
#pragma unroll
      for (int msk = 8; msk >= 1; msk >>= 1) sm += __shfl_xor(sm, msk);
      float inv = 1.0f / sm;
      pr[mb][0][r] = e0 * inv;
      pr[mb][1][r] = e1 * inv;
    }

  __syncthreads();
#pragma unroll
  for (int mb = 0; mb < 2; ++mb)
#pragma unroll
    for (int nb = 0; nb < 2; ++nb)
#pragma unroll
      for (int r = 0; r < 4; ++r)
        Plds[(mb * 16 + lg * 4 + r) * 32 + nb * 16 + l16] = (bf16)pr[mb][nb][r];
  __syncthreads();

  bf16x8 pa[2], vb[4];
#pragma unroll
  for (int mb = 0; mb < 2; ++mb)
    pa[mb] = *(const bf16x8*)&Plds[(mb * 16 + l16) * 32 + lg * 8];
#pragma unroll
  for (int nb = 0; nb < 4; ++nb)
    vb[nb] = *(const bf16x8*)&vT[(nb * 16 + l16) * 32 + lg * 8];
  f32x4 oc[2][4] = {};
#pragma unroll
  for (int mb = 0; mb < 2; ++mb)
#pragma unroll
    for (int nb = 0; nb < 4; ++nb)
      oc[mb][nb] = __builtin_amdgcn_mfma_f32_16x16x32_bf16(pa[mb], vb[nb], oc[mb][nb], 0, 0, 0);

#pragma unroll
  for (int mb = 0; mb < 2; ++mb)
#pragma unroll
    for (int nb = 0; nb < 4; ++nb)
#pragma unroll
      for (int r = 0; r < 4; ++r) {
        const int m = mb * 16 + lg * 4 + r;
        const int s = par + 2 * m;
        qkv[base + (long)s * NQKV + h * 64 + nb * 16 + l16] = (bf16)oc[mb][nb][r];
      }
  const uint4 z = make_uint4(0, 0, 0, 0);
#pragma unroll
  for (int it = 0; it < 4; ++it) {
    const int r2 = it * 8 + (lane >> 3);
    const int s = (1 - par) + 2 * r2;
    *(uint4*)(qkv + base + (long)s * NQKV + h * 64 + (lane & 7) * 8) = z;
  }
}

// ---------------- host-side orchestration --------------------------------------------
extern "C" void kernel_launch(void* const* d_in, const int* in_sizes, int n_in,
                              void* d_out, int out_size, void* d_ws, size_t ws_size,
                              hipStream_t stream)
{
  const float* x     = (const float*)d_in[0];
  const float* gamma = (const float*)d_in[1];
  const float* wq = (const float*)d_in[2];  const float* bq = (const float*)d_in[3];
  const float* wk = (const float*)d_in[4];  const float* bk = (const float*)d_in[5];
  const float* wv = (const float*)d_in[6];  const float* bv = (const float*)d_in[7];
  const float* wo = (const float*)d_in[8];  const float* bo = (const float*)d_in[9];
  const float* ffg = (const float*)d_in[10]; const float* ffb = (const float*)d_in[11];
  const float* w1 = (const float*)d_in[12]; const float* b1 = (const float*)d_in[13];
  const float* w2 = (const float*)d_in[14]; const float* b2 = (const float*)d_in[15];

  char* p = (char*)d_ws;
  bf16* Wqkv_t = (bf16*)p; p += (size_t)NQKV * DM * 2;   // tiled-swizzled
  bf16* Wo_t   = (bf16*)p; p += (size_t)DM * DM * 2;     // row-major
  bf16* W1_t   = (bf16*)p; p += (size_t)DFF * DM * 2;    // tiled-swizzled
  bf16* W2_t   = (bf16*)p; p += (size_t)DM * DFF * 2;    // row-major
  float* bqkv  = (float*)p; p += (size_t)NQKV * 4;
  bf16* hbuf   = (bf16*)p; p += (size_t)NTOK * DM * 2;   // tiled-swizzled
  bf16* qkv    = (bf16*)p; p += (size_t)NTOK * DFF * 2;  // row-major
  float* xnew  = (float*)d_out;

  dim3 b256(256);
  transpose_cvt_tiled<<<dim3(32, 32, 3),  b256, 0, stream>>>(wq, wk, wv, Wqkv_t, DM, DM);
  transpose_cvt      <<<dim3(32, 32),     b256, 0, stream>>>(wo, Wo_t, DM, DM);
  transpose_cvt_tiled<<<dim3(128, 32, 1), b256, 0, stream>>>(w1, w1, w1, W1_t, DM, DFF);
  transpose_cvt      <<<dim3(32, 128),    b256, 0, stream>>>(w2, W2_t, DFF, DM);
  concat_bias<<<12, b256, 0, stream>>>(bq, bk, bv, bqkv);

  ln1_kernel<<<NTOK, b256, 0, stream>>>(x, gamma, hbuf);

  // QKV GEMM (K=1024, tiled BK=32 counted): h @ [wq|wk|wv] -> qkv bf16 [16384][3072]
  gemm32c<0><<<dim3(128 * 24), b256, 0, stream>>>(
      hbuf, Wqkv_t, bqkv, nullptr, 0, qkv, NQKV, DM, 128 * 24);

  attn_kernel<<<1024, b256, 0, stream>>>(qkv);

  // WO GEMM (K=3072, BK=64 stage-before-MFMA) + residual -> xnew fp32 (d_out)
  gemm64d<1><<<dim3(128 * 8), b256, 0, stream>>>(
      qkv, NQKV, Wo_t, bo, x, DM, xnew, DM, DM, 128 * 8);

  ln2_kernel<<<NTOK, b256, 0, stream>>>(xnew, gamma, ffg, ffb, hbuf);

  // FFN1 + GELU (K=1024, tiled BK=32 counted) -> g1 bf16 [16384][4096]
  gemm32c<2><<<dim3(128 * 32), b256, 0, stream>>>(
      hbuf, W1_t, b1, nullptr, 0, qkv, DFF, DM, 128 * 32);

  // FFN2 (K=4096, BK=64 stage-before-MFMA) + residual -> d_out fp32
  gemm64d<1><<<dim3(128 * 8), b256, 0, stream>>>(
      qkv, DFF, W2_t, b2, xnew, DM, (float*)d_out, DM, DFF, 128 * 8);
}